// Round 2
// baseline (349.910 us; speedup 1.0000x reference)
//
#include <hip/hip_runtime.h>
#include <math.h>

#define BATCH 8192
#define NROW 512
#define NCOL 512
#define MNODE 256

typedef __attribute__((ext_vector_type(8))) short bf16x8;
typedef __attribute__((ext_vector_type(4))) float f32x4;

// Split fp32 into truncated-bf16 hi + bf16(lo residual). a ~= hi + lo.
// Returns packed in a short2 (x=h, y=l) to avoid reference-to-vector-element.
__device__ __forceinline__ short2 split1(float x) {
  unsigned u = __float_as_uint(x);
  short h = (short)(u >> 16);
  float r = x - __uint_as_float(u & 0xffff0000u);
  short l = (short)(__float_as_uint(r) >> 16);
  return make_short2(h, l);
}

// ---------------------------------------------------------------------------
// Fused per-node 2x2 complex matrix (verified rounds 1-7).
// pp[2n+0]=(n11r,n11i,n12r,n12i); pp[2n+1]=(n21r,n21i,n22r,n22i)
// ---------------------------------------------------------------------------
__global__ __launch_bounds__(256) void precomp_kernel(
    const float* __restrict__ thetas, const float* __restrict__ phis,
    const float* __restrict__ bse, const float* __restrict__ lse,
    float4* __restrict__ pp) {
  int n = blockIdx.x * 256 + threadIdx.x;
  float th = thetas[n], ph = phis[n];
  float e0 = bse[2 * n + 0], e1 = bse[2 * n + 1];
  float l0 = lse[2 * n + 0], l1 = lse[2 * n + 1];
  const float K = 0.16609640474436813f;  // log2(10)/20
  float ins0 = exp2f(l0 * K), ins1 = exp2f(l1 * K);
  const float PI4 = 0.7853981633974483f;
  float s0, c0, s1, c1, sp, cp, st, ct;
  sincosf(PI4 + e0, &s0, &c0);
  sincosf(PI4 + e1, &s1, &c1);
  sincosf(ph, &sp, &cp);
  sincosf(th, &st, &ct);
  float AL = ins0 * s0, C1L = c0, C2L = ins0 * c0, SL = s0;
  float AR = ins1 * s1, C1R = c1, C2R = ins1 * c1, SR = s1;
  float a11r = AL * cp,   a11i = AL * sp;
  float a12r = 0.f,       a12i = C1L;
  float a21r = -C2L * sp, a21i = C2L * cp;
  float a22r = SL,        a22i = 0.f;
  float b11r = a11r * ct - a11i * st, b11i = a11r * st + a11i * ct;
  float b12r = a12r * ct - a12i * st, b12i = a12r * st + a12i * ct;
  float n11r = AR * b11r - C1R * a21i;
  float n11i = AR * b11i + C1R * a21r;
  float n12r = AR * b12r - C1R * a22i;
  float n12i = AR * b12i + C1R * a22r;
  float n21r = -C2R * b11i + SR * a21r;
  float n21i =  C2R * b11r + SR * a21i;
  float n22r = -C2R * b12i + SR * a22r;
  float n22i =  C2R * b12r + SR * a22i;
  pp[2 * n + 0] = make_float4(n11r, n11i, n12r, n12i);
  pp[2 * n + 1] = make_float4(n21r, n21i, n22r, n22i);
}

__device__ __forceinline__ void proc_pair(float& vtr, float& vti, float& vbr, float& vbi,
                                          const float4 q0, const float4 q1) {
  float tr = q0.x * vtr - q0.y * vti + q0.z * vbr - q0.w * vbi;
  float ti = q0.x * vti + q0.y * vtr + q0.z * vbi + q0.w * vbr;
  float br = q1.x * vtr - q1.y * vti + q1.z * vbr - q1.w * vbi;
  float bi = q1.x * vti + q1.y * vtr + q1.z * vbi + q1.w * vbr;
  vtr = tr; vti = ti; vbr = br; vbi = bi;
}

// ---------------------------------------------------------------------------
// SEGMENTED COMPOSE, GLOBAL-DIRECT + BAND PREDICATION (round 2).
// No LDS tile, no per-iteration barrier: each lane reads its 2x2 fragments
// directly from global (pp seg slice is 512 KB, L2-resident; 128 B
// contiguous per lane, fully coalesced, band-predicated). Waves proceed
// independently — L2 latency overlaps across waves instead of being
// serialized through a block-wide __syncthreads each pair-column.
// Basis column `col` has support within [col-2p, col+2p] before tile p;
// lanes outside the (margined) band hold exact zeros and skip everything.
// ---------------------------------------------------------------------------
__global__ __launch_bounds__(256) void compose_kernel(
    const float* __restrict__ gammas, const float4* __restrict__ pp,
    float* __restrict__ Tsegs, int pairs_per_seg) {
  __shared__ float ep[1024][5];

  const int tid  = threadIdx.x;
  const int lane = tid & 63;
  const int w    = tid >> 6;
  const int seg  = blockIdx.x >> 7;
  const int g    = blockIdx.x & 127;
  const int col  = g * 4 + w;

  const float4* ps = pp + (size_t)seg * pairs_per_seg * 1024;
  float* T = Tsegs + (size_t)seg * (1024 * NROW);

  float vr[8], vi[8];
#pragma unroll
  for (int r = 0; r < 8; ++r) {
    const int row = lane * 8 + r;
    vr[r] = 0.f; vi[r] = 0.f;
    if (row == col) {
      if (seg == 0) {
        float sg, cg;
        sincosf(gammas[row], &sg, &cg);
        vr[r] = cg; vi[r] = sg;
      } else {
        vr[r] = 1.f;
      }
    }
  }

  const int Lc = col >> 3;  // center lane of this wave's band

#pragma unroll 1
  for (int p = 0; p < pairs_per_seg; ++p) {
    // Band predicates. HA = floor(p/4)+3 lanes covers support growth
    // [col-2p-2, col+2p+2] with >=1 lane to spare (8*(p/4+3) >= 2p+9).
    // `wide` (one lane extra each side) executes shuffles so every act
    // lane's shuffle source is defined (and exactly zero).
    const int HA = (p >> 2) + 3;
    const bool act  = (lane >= Lc - HA)     && (lane <= Lc + HA);
    const bool wide = (lane >= Lc - HA - 1) && (lane <= Lc + HA + 1);

    float4 pe[8], po[7], pu1;
    if (act) {
      // pe: even-pair 2x2 halves, rows 8*lane..8*lane+7 (128 B contiguous)
      // po: odd-pair halves at +512; pu1: previous lane's po[7].
      const float4* rowp = ps + (size_t)p * 1024 + 8 * lane;
#pragma unroll
      for (int j = 0; j < 8; ++j) pe[j] = rowp[j];
#pragma unroll
      for (int j = 0; j < 7; ++j) po[j] = rowp[512 + j];
      const int lm = (lane == 0) ? 0 : lane - 1;
      pu1 = ps[(size_t)p * 1024 + 512 + 8 * lm + 7];

#pragma unroll
      for (int k = 0; k < 4; ++k)
        proc_pair(vr[2 * k], vi[2 * k], vr[2 * k + 1], vi[2 * k + 1],
                  pe[2 * k], pe[2 * k + 1]);

#pragma unroll
      for (int k = 0; k < 3; ++k)
        proc_pair(vr[2 * k + 1], vi[2 * k + 1], vr[2 * k + 2], vi[2 * k + 2],
                  po[2 * k], po[2 * k + 1]);
    }

    float br = 0.f, bi = 0.f, tu = 0.f, tv = 0.f;
    if (wide) {
      br = __shfl_down(vr[0], 1, 64);
      bi = __shfl_down(vi[0], 1, 64);
      tu = __shfl_up(vr[7], 1, 64);
      tv = __shfl_up(vi[7], 1, 64);
    }
    if (act) {
      float nAr = po[6].x * vr[7] - po[6].y * vi[7] + po[6].z * br - po[6].w * bi;
      float nAi = po[6].x * vi[7] + po[6].y * vr[7] + po[6].z * bi + po[6].w * br;
      float nBr = pu1.x * tu - pu1.y * tv + pu1.z * vr[0] - pu1.w * vi[0];
      float nBi = pu1.x * tv + pu1.y * tu + pu1.z * vi[0] + pu1.w * vr[0];
      if (lane < 63) { vr[7] = nAr; vi[7] = nAi; }
      if (lane > 0)  { vr[0] = nBr; vi[0] = nBi; }
    }
  }

#pragma unroll
  for (int r = 0; r < 8; ++r) {
    ep[lane * 8 + r][w] = vr[r];
    ep[512 + lane * 8 + r][w] = vi[r];
  }
  __syncthreads();
#pragma unroll
  for (int k = 0; k < 4; ++k) {
    const int i = k * 256 + tid;
    *(float4*)(T + (size_t)i * NROW + g * 4) =
        make_float4(ep[i][0], ep[i][1], ep[i][2], ep[i][3]);
  }
}

// ---------------------------------------------------------------------------
// MERGE (MFMA, bf16-split): complex 512^3 as real GEMM
//   C_stack[1024x512] = A'[1024x1024] * B_stack[1024x512]
// A' = [[Ar,-Ai],[Ai,Ar]] materialized in staging (sign-twiddled loads).
// Fragment layouts: a-frag A[m=lane&15][k=quad*8+j], b-frag B[k=quad*8+j][n=lane&15],
// D[row=quad*4+reg][col=lane&15].  BM=BN=64, BK=32; grid (8,16,z).
// ---------------------------------------------------------------------------
__global__ __launch_bounds__(256) void merge_mfma(
    const float* __restrict__ A0, const float* __restrict__ B0, float* __restrict__ C0,
    const float* __restrict__ A1, const float* __restrict__ B1, float* __restrict__ C1) {
  const float* A = blockIdx.z ? A1 : A0;
  const float* B = blockIdx.z ? B1 : B0;
  float*       C = blockIdx.z ? C1 : C0;

  __shared__ short sAh[64 * 40], sAl[64 * 40];  // [m][k] bf16, stride 40

  const int tid = threadIdx.x;
  const int lane = tid & 63;
  const int w = tid >> 6;
  const int bm = blockIdx.y * 64;
  const int bn = blockIdx.x * 64;
  const int wm = (w & 1) * 32;
  const int wn = (w >> 1) * 32;
  const int q = lane >> 4;
  const int l15 = lane & 15;

  const int sm = tid >> 2;          // 0..63 staged row
  const int sk = (tid & 3) * 8;     // 0..24 staged k-offset

  f32x4 acc[2][2];
#pragma unroll
  for (int i = 0; i < 2; ++i)
#pragma unroll
    for (int j = 0; j < 2; ++j) acc[i][j] = (f32x4){0.f, 0.f, 0.f, 0.f};

#pragma unroll 1
  for (int k0 = 0; k0 < 1024; k0 += 32) {
    // stage A' tile [64m x 32k] with quadrant select + sign
    {
      const int gm = bm + sm;
      const int gk = k0 + sk;
      const int r = gm & 511;
      const bool top = gm < 512;
      const bool left = gk < 512;
      const int col = gk & 511;
      const float* src = (top == left) ? (A + (size_t)r * 512)
                                       : (A + (size_t)(512 + r) * 512);
      const float sgn = (top && !left) ? -1.f : 1.f;
      float4 v0 = *(const float4*)(src + col);
      float4 v1 = *(const float4*)(src + col + 4);
      float vv[8] = {v0.x, v0.y, v0.z, v0.w, v1.x, v1.y, v1.z, v1.w};
      short h[8], l[8];
#pragma unroll
      for (int i = 0; i < 8; ++i) {
        short2 s = split1(sgn * vv[i]);
        h[i] = s.x; l[i] = s.y;
      }
      __syncthreads();
      *(bf16x8*)&sAh[sm * 40 + sk] = *(bf16x8*)h;
      *(bf16x8*)&sAl[sm * 40 + sk] = *(bf16x8*)l;
      __syncthreads();
    }

    // gather + split B fragments (B_stack is [1024][512], k-major gather)
    bf16x8 bh[2], bl[2];
#pragma unroll
    for (int nt = 0; nt < 2; ++nt) {
      const float* bp = B + (size_t)(k0 + q * 8) * 512 + bn + wn + nt * 16 + l15;
      short hh[8], ll[8];
#pragma unroll
      for (int j = 0; j < 8; ++j) {
        short2 s = split1(bp[(size_t)j * 512]);
        hh[j] = s.x; ll[j] = s.y;
      }
      bh[nt] = *(bf16x8*)hh;
      bl[nt] = *(bf16x8*)ll;
    }

    // read A fragments
    bf16x8 ah[2], al[2];
#pragma unroll
    for (int mt = 0; mt < 2; ++mt) {
      const int m = wm + mt * 16 + l15;
      ah[mt] = *(const bf16x8*)&sAh[m * 40 + q * 8];
      al[mt] = *(const bf16x8*)&sAl[m * 40 + q * 8];
    }

#pragma unroll
    for (int mt = 0; mt < 2; ++mt)
#pragma unroll
      for (int nt = 0; nt < 2; ++nt) {
        acc[mt][nt] = __builtin_amdgcn_mfma_f32_16x16x32_bf16(ah[mt], bh[nt], acc[mt][nt], 0, 0, 0);
        acc[mt][nt] = __builtin_amdgcn_mfma_f32_16x16x32_bf16(ah[mt], bl[nt], acc[mt][nt], 0, 0, 0);
        acc[mt][nt] = __builtin_amdgcn_mfma_f32_16x16x32_bf16(al[mt], bh[nt], acc[mt][nt], 0, 0, 0);
      }
  }

#pragma unroll
  for (int mt = 0; mt < 2; ++mt)
#pragma unroll
    for (int nt = 0; nt < 2; ++nt)
#pragma unroll
      for (int r = 0; r < 4; ++r) {
        const int gm = bm + wm + mt * 16 + q * 4 + r;
        const int gn = bn + wn + nt * 16 + l15;
        C[(size_t)gm * 512 + gn] = acc[mt][nt][r];
      }
}

// ---------------------------------------------------------------------------
// APPLY (MFMA, bf16-split): C[1024x8192] = A[1024x512] * B(x)[512x8192].
// A staged in LDS ([m][k] bf16 hi/lo, stride 40); B gathered per-lane from
// global (k-stride dwords, L2-resident) + in-reg split.
// BM=BN=128, BK=32; wave tile 64x64 (acc 64 VGPR).
// ---------------------------------------------------------------------------
__global__ __launch_bounds__(256) void gemm_mfma(
    const float* __restrict__ A, const float* __restrict__ B,
    float* __restrict__ C) {
  __shared__ short sAh[128 * 40], sAl[128 * 40];

  const int tid = threadIdx.x;
  const int lane = tid & 63;
  const int w = tid >> 6;
  const int bm = blockIdx.y * 128;
  const int bn = blockIdx.x * 128;
  const int wm = (w & 1) * 64;
  const int wn = (w >> 1) * 64;
  const int q = lane >> 4;
  const int l15 = lane & 15;

  const int sm = tid >> 1;          // 0..127 staged row
  const int sk = (tid & 1) * 16;    // 0 or 16
  const float* Ap = A + (size_t)(bm + sm) * 512 + sk;

  f32x4 acc[4][4];
#pragma unroll
  for (int i = 0; i < 4; ++i)
#pragma unroll
    for (int j = 0; j < 4; ++j) acc[i][j] = (f32x4){0.f, 0.f, 0.f, 0.f};

  // prefetch first A slab (16 floats/thread)
  float4 pa[4];
#pragma unroll
  for (int i = 0; i < 4; ++i) pa[i] = *(const float4*)(Ap + i * 4);

#pragma unroll 1
  for (int k0 = 0; k0 < 512; k0 += 32) {
    // stage A slab
    {
      short h[16], l[16];
#pragma unroll
      for (int i = 0; i < 16; ++i) {
        short2 s = split1(((const float*)pa)[i]);
        h[i] = s.x; l[i] = s.y;
      }
      __syncthreads();
      *(bf16x8*)&sAh[sm * 40 + sk]     = *(bf16x8*)&h[0];
      *(bf16x8*)&sAh[sm * 40 + sk + 8] = *(bf16x8*)&h[8];
      *(bf16x8*)&sAl[sm * 40 + sk]     = *(bf16x8*)&l[0];
      *(bf16x8*)&sAl[sm * 40 + sk + 8] = *(bf16x8*)&l[8];
      __syncthreads();
    }

    // prefetch next A slab
    if (k0 + 32 < 512) {
#pragma unroll
      for (int i = 0; i < 4; ++i) pa[i] = *(const float4*)(Ap + k0 + 32 + i * 4);
    }

    // gather B fp32 (k-major), split in-register
    bf16x8 bh[4], bl[4];
#pragma unroll
    for (int nt = 0; nt < 4; ++nt) {
      const float* bp = B + (size_t)(k0 + q * 8) * BATCH + bn + wn + nt * 16 + l15;
      short hh[8], ll[8];
#pragma unroll
      for (int j = 0; j < 8; ++j) {
        short2 s = split1(bp[(size_t)j * BATCH]);
        hh[j] = s.x; ll[j] = s.y;
      }
      bh[nt] = *(bf16x8*)hh;
      bl[nt] = *(bf16x8*)ll;
    }

    // read A fragments
    bf16x8 ah[4], al[4];
#pragma unroll
    for (int mt = 0; mt < 4; ++mt) {
      const int m = wm + mt * 16 + l15;
      ah[mt] = *(const bf16x8*)&sAh[m * 40 + q * 8];
      al[mt] = *(const bf16x8*)&sAl[m * 40 + q * 8];
    }

#pragma unroll
    for (int mt = 0; mt < 4; ++mt)
#pragma unroll
      for (int nt = 0; nt < 4; ++nt) {
        acc[mt][nt] = __builtin_amdgcn_mfma_f32_16x16x32_bf16(ah[mt], bh[nt], acc[mt][nt], 0, 0, 0);
        acc[mt][nt] = __builtin_amdgcn_mfma_f32_16x16x32_bf16(ah[mt], bl[nt], acc[mt][nt], 0, 0, 0);
        acc[mt][nt] = __builtin_amdgcn_mfma_f32_16x16x32_bf16(al[mt], bh[nt], acc[mt][nt], 0, 0, 0);
      }
  }

  // epilogue: D[row=q*4+r][col=l15] per 16x16 tile
#pragma unroll
  for (int mt = 0; mt < 4; ++mt)
#pragma unroll
    for (int nt = 0; nt < 4; ++nt)
#pragma unroll
      for (int r = 0; r < 4; ++r) {
        const int gm = bm + wm + mt * 16 + q * 4 + r;
        const int gn = bn + wn + nt * 16 + l15;
        C[(size_t)gm * BATCH + gn] = acc[mt][nt][r];
      }
}

extern "C" void kernel_launch(void* const* d_in, const int* in_sizes, int n_in,
                              void* d_out, int out_size, void* d_ws, size_t ws_size,
                              hipStream_t stream) {
  const float* x      = (const float*)d_in[0];
  const float* thetas = (const float*)d_in[1];
  const float* phis   = (const float*)d_in[2];
  const float* gammas = (const float*)d_in[3];
  const float* bse    = (const float*)d_in[4];
  const float* lse    = (const float*)d_in[5];
  // top/bottom/mask (d_in[6..8]) deterministic (Clements mesh) — derived analytically.

  float* base = (float*)d_ws;
  float4* pp  = (float4*)d_ws;
  const size_t PPF   = 1048576;   // 4 MB of floats (pp region)
  const size_t SEGSZ = 524288;    // 2 MB per seg transfer matrix

  int nseg;
  if (ws_size >= (size_t)24 * 1024 * 1024)      nseg = 8;
  else if (ws_size >= (size_t)14 * 1024 * 1024) nseg = 4;
  else if (ws_size >= (size_t)8 * 1024 * 1024)  nseg = 2;
  else                                          nseg = 1;

  float* segs = base + PPF;
  float* Tf;

  precomp_kernel<<<512, 256, 0, stream>>>(thetas, phis, bse, lse, pp);
  compose_kernel<<<nseg * 128, 256, 0, stream>>>(gammas, pp, segs, 256 / nseg);

  if (nseg == 8) {
    float* T[8];
    for (int s = 0; s < 8; ++s) T[s] = segs + (size_t)s * SEGSZ;
    // level 1: pairwise merges. Outputs: T10,T32 in base (pp dead after
    // compose); T54,T76 after the 8 segs ([20,24) MB).
    float* T10 = base;
    float* T32 = base + SEGSZ;
    float* T54 = segs + 8 * SEGSZ;
    float* T76 = segs + 9 * SEGSZ;
    merge_mfma<<<dim3(8, 16, 2), 256, 0, stream>>>(T[1], T[0], T10, T[3], T[2], T32);
    merge_mfma<<<dim3(8, 16, 2), 256, 0, stream>>>(T[5], T[4], T54, T[7], T[6], T76);
    // level 2: outputs overwrite dead T0..T3 region.
    float* T3210 = segs;
    float* T7654 = segs + SEGSZ;
    merge_mfma<<<dim3(8, 16, 2), 256, 0, stream>>>(T32, T10, T3210, T76, T54, T7654);
    // level 3: final into base (T10/T32 dead).
    Tf = base;
    merge_mfma<<<dim3(8, 16, 1), 256, 0, stream>>>(T7654, T3210, Tf, T7654, T3210, Tf);
  } else if (nseg == 4) {
    float* T0  = segs + 0 * SEGSZ;
    float* T1  = segs + 1 * SEGSZ;
    float* T2  = segs + 2 * SEGSZ;
    float* T3  = segs + 3 * SEGSZ;
    float* T10 = base;                 // pp region dead after compose
    float* T32 = base + SEGSZ;
    Tf = segs + 4 * SEGSZ;
    merge_mfma<<<dim3(8, 16, 2), 256, 0, stream>>>(T1, T0, T10, T3, T2, T32);
    merge_mfma<<<dim3(8, 16, 1), 256, 0, stream>>>(T32, T10, Tf, T32, T10, Tf);
  } else if (nseg == 2) {
    float* T0 = segs + 0 * SEGSZ;
    float* T1 = segs + 1 * SEGSZ;
    Tf = base;
    merge_mfma<<<dim3(8, 16, 1), 256, 0, stream>>>(T1, T0, Tf, T1, T0, Tf);
  } else {
    Tf = segs;
  }

  // final apply: C[1024x8192] = Tf * x (only kernel touching d_out)
  gemm_mfma<<<dim3(BATCH / 128, 8), 256, 0, stream>>>(Tf, x, (float*)d_out);
}

// Round 3
// 266.765 us; speedup vs baseline: 1.3117x; 1.3117x over previous
//
#include <hip/hip_runtime.h>
#include <math.h>

#define BATCH 8192
#define NROW 512
#define NCOL 512
#define MNODE 256

typedef __attribute__((ext_vector_type(8))) short bf16x8;
typedef __attribute__((ext_vector_type(4))) float f32x4;

// Split fp32 into truncated-bf16 hi + bf16(lo residual). a ~= hi + lo.
__device__ __forceinline__ short2 split1(float x) {
  unsigned u = __float_as_uint(x);
  short h = (short)(u >> 16);
  float r = x - __uint_as_float(u & 0xffff0000u);
  short l = (short)(__float_as_uint(r) >> 16);
  return make_short2(h, l);
}

// ---------------------------------------------------------------------------
// Fused per-node 2x2 complex matrix (verified rounds 1-7).
// pp[2n+0]=(n11r,n11i,n12r,n12i); pp[2n+1]=(n21r,n21i,n22r,n22i)
// ---------------------------------------------------------------------------
__global__ __launch_bounds__(256) void precomp_kernel(
    const float* __restrict__ thetas, const float* __restrict__ phis,
    const float* __restrict__ bse, const float* __restrict__ lse,
    float4* __restrict__ pp) {
  int n = blockIdx.x * 256 + threadIdx.x;
  float th = thetas[n], ph = phis[n];
  float e0 = bse[2 * n + 0], e1 = bse[2 * n + 1];
  float l0 = lse[2 * n + 0], l1 = lse[2 * n + 1];
  const float K = 0.16609640474436813f;  // log2(10)/20
  float ins0 = exp2f(l0 * K), ins1 = exp2f(l1 * K);
  const float PI4 = 0.7853981633974483f;
  float s0, c0, s1, c1, sp, cp, st, ct;
  sincosf(PI4 + e0, &s0, &c0);
  sincosf(PI4 + e1, &s1, &c1);
  sincosf(ph, &sp, &cp);
  sincosf(th, &st, &ct);
  float AL = ins0 * s0, C1L = c0, C2L = ins0 * c0, SL = s0;
  float AR = ins1 * s1, C1R = c1, C2R = ins1 * c1, SR = s1;
  float a11r = AL * cp,   a11i = AL * sp;
  float a12r = 0.f,       a12i = C1L;
  float a21r = -C2L * sp, a21i = C2L * cp;
  float a22r = SL,        a22i = 0.f;
  float b11r = a11r * ct - a11i * st, b11i = a11r * st + a11i * ct;
  float b12r = a12r * ct - a12i * st, b12i = a12r * st + a12i * ct;
  float n11r = AR * b11r - C1R * a21i;
  float n11i = AR * b11i + C1R * a21r;
  float n12r = AR * b12r - C1R * a22i;
  float n12i = AR * b12i + C1R * a22r;
  float n21r = -C2R * b11i + SR * a21r;
  float n21i =  C2R * b11r + SR * a21i;
  float n22r = -C2R * b12i + SR * a22r;
  float n22i =  C2R * b12r + SR * a22i;
  pp[2 * n + 0] = make_float4(n11r, n11i, n12r, n12i);
  pp[2 * n + 1] = make_float4(n21r, n21i, n22r, n22i);
}

__device__ __forceinline__ void proc_pair(float& vtr, float& vti, float& vbr, float& vbi,
                                          const float4 q0, const float4 q1) {
  float tr = q0.x * vtr - q0.y * vti + q0.z * vbr - q0.w * vbi;
  float ti = q0.x * vti + q0.y * vtr + q0.z * vbi + q0.w * vbr;
  float br = q1.x * vtr - q1.y * vti + q1.z * vbr - q1.w * vbi;
  float bi = q1.x * vti + q1.y * vtr + q1.z * vbi + q1.w * vbr;
  vtr = tr; vti = ti; vbr = br; vbi = bi;
}

__device__ __forceinline__ int swz(int b) { return b ^ ((b >> 3) & 7); }

// ---------------------------------------------------------------------------
// SEGMENTED COMPOSE with BAND PREDICATION (round-1 verified version, 86 us).
// LDS-staged double-buffered tile; band predication on LDS reads/compute.
// ---------------------------------------------------------------------------
__global__ __launch_bounds__(256) void compose_kernel(
    const float* __restrict__ gammas, const float4* __restrict__ pp,
    float* __restrict__ Tsegs, int pairs_per_seg) {
  __shared__ float4 buf[2][1024];
  __shared__ float ep[1024][5];

  const int tid  = threadIdx.x;
  const int lane = tid & 63;
  const int w    = tid >> 6;
  const int seg  = blockIdx.x >> 7;
  const int g    = blockIdx.x & 127;
  const int col  = g * 4 + w;
  const int colmin = g * 4;   // block-uniform band center for staging

  const float4* ps = pp + (size_t)seg * pairs_per_seg * 1024;
  float* T = Tsegs + (size_t)seg * (1024 * NROW);

  float vr[8], vi[8];
#pragma unroll
  for (int r = 0; r < 8; ++r) {
    const int row = lane * 8 + r;
    vr[r] = 0.f; vi[r] = 0.f;
    if (row == col) {
      if (seg == 0) {
        float sg, cg;
        sincosf(gammas[row], &sg, &cg);
        vr[r] = cg; vi[r] = sg;
      } else {
        vr[r] = 1.f;
      }
    }
  }

  {
    const int sw = swz(tid);
#pragma unroll
    for (int k = 0; k < 4; ++k)
      buf[0][256 * k + sw] = ps[256 * k + tid];
  }
  __syncthreads();

  const int Lc = col >> 3;  // center lane of this wave's band

#pragma unroll 1
  for (int p = 0; p < pairs_per_seg; ++p) {
    const int b = p & 1;

    const int HA = (p >> 2) + 3;
    const bool act  = (lane >= Lc - HA)     && (lane <= Lc + HA);
    const bool wide = (lane >= Lc - HA - 1) && (lane <= Lc + HA + 1);

    float4 f0, f1, f2, f3;
    bool st0 = false, st1 = false;
    if (p < pairs_per_seg - 1) {
      const int slo = colmin - 2 * p - 50;
      const int shi = colmin + 2 * p + 53;
      st0 = (tid + 1 >= slo) && (tid <= shi);
      st1 = (tid + 257 >= slo) && (tid + 256 <= shi);
      const float4* src = ps + (size_t)(p + 1) * 1024;
      if (st0) { f0 = src[tid];       f2 = src[512 + tid]; }
      if (st1) { f1 = src[256 + tid]; f3 = src[768 + tid]; }
    }

    float4 pe[8], po[7], pu1;
    if (act) {
      const int base = 8 * lane;
      const int l7 = lane & 7;
#pragma unroll
      for (int j = 0; j < 8; ++j) pe[j] = buf[b][base + (j ^ l7)];
#pragma unroll
      for (int j = 0; j < 7; ++j) po[j] = buf[b][512 + base + (j ^ l7)];
      const int lm = (lane == 0) ? 0 : lane - 1;
      pu1 = buf[b][512 + 8 * lm + (7 ^ (lm & 7))];

#pragma unroll
      for (int k = 0; k < 4; ++k)
        proc_pair(vr[2 * k], vi[2 * k], vr[2 * k + 1], vi[2 * k + 1],
                  pe[2 * k], pe[2 * k + 1]);

#pragma unroll
      for (int k = 0; k < 3; ++k)
        proc_pair(vr[2 * k + 1], vi[2 * k + 1], vr[2 * k + 2], vi[2 * k + 2],
                  po[2 * k], po[2 * k + 1]);
    }

    float br = 0.f, bi = 0.f, tu = 0.f, tv = 0.f;
    if (wide) {
      br = __shfl_down(vr[0], 1, 64);
      bi = __shfl_down(vi[0], 1, 64);
      tu = __shfl_up(vr[7], 1, 64);
      tv = __shfl_up(vi[7], 1, 64);
    }
    if (act) {
      float nAr = po[6].x * vr[7] - po[6].y * vi[7] + po[6].z * br - po[6].w * bi;
      float nAi = po[6].x * vi[7] + po[6].y * vr[7] + po[6].z * bi + po[6].w * br;
      float nBr = pu1.x * tu - pu1.y * tv + pu1.z * vr[0] - pu1.w * vi[0];
      float nBi = pu1.x * tv + pu1.y * tu + pu1.z * vi[0] + pu1.w * vr[0];
      if (lane < 63) { vr[7] = nAr; vi[7] = nAi; }
      if (lane > 0)  { vr[0] = nBr; vi[0] = nBi; }
    }

    if (p < pairs_per_seg - 1) {
      const int sw = swz(tid);
      if (st0) { buf[1 - b][sw] = f0;       buf[1 - b][512 + sw] = f2; }
      if (st1) { buf[1 - b][256 + sw] = f1; buf[1 - b][768 + sw] = f3; }
    }
    __syncthreads();
  }

#pragma unroll
  for (int r = 0; r < 8; ++r) {
    ep[lane * 8 + r][w] = vr[r];
    ep[512 + lane * 8 + r][w] = vi[r];
  }
  __syncthreads();
#pragma unroll
  for (int k = 0; k < 4; ++k) {
    const int i = k * 256 + tid;
    *(float4*)(T + (size_t)i * NROW + g * 4) =
        make_float4(ep[i][0], ep[i][1], ep[i][2], ep[i][3]);
  }
}

// ---------------------------------------------------------------------------
// MERGE (MFMA, bf16-split): complex 512^3 as real GEMM (unchanged, verified).
// ---------------------------------------------------------------------------
__global__ __launch_bounds__(256) void merge_mfma(
    const float* __restrict__ A0, const float* __restrict__ B0, float* __restrict__ C0,
    const float* __restrict__ A1, const float* __restrict__ B1, float* __restrict__ C1) {
  const float* A = blockIdx.z ? A1 : A0;
  const float* B = blockIdx.z ? B1 : B0;
  float*       C = blockIdx.z ? C1 : C0;

  __shared__ short sAh[64 * 40], sAl[64 * 40];  // [m][k] bf16, stride 40

  const int tid = threadIdx.x;
  const int lane = tid & 63;
  const int w = tid >> 6;
  const int bm = blockIdx.y * 64;
  const int bn = blockIdx.x * 64;
  const int wm = (w & 1) * 32;
  const int wn = (w >> 1) * 32;
  const int q = lane >> 4;
  const int l15 = lane & 15;

  const int sm = tid >> 2;          // 0..63 staged row
  const int sk = (tid & 3) * 8;     // 0..24 staged k-offset

  f32x4 acc[2][2];
#pragma unroll
  for (int i = 0; i < 2; ++i)
#pragma unroll
    for (int j = 0; j < 2; ++j) acc[i][j] = (f32x4){0.f, 0.f, 0.f, 0.f};

#pragma unroll 1
  for (int k0 = 0; k0 < 1024; k0 += 32) {
    // stage A' tile [64m x 32k] with quadrant select + sign
    {
      const int gm = bm + sm;
      const int gk = k0 + sk;
      const int r = gm & 511;
      const bool top = gm < 512;
      const bool left = gk < 512;
      const int col = gk & 511;
      const float* src = (top == left) ? (A + (size_t)r * 512)
                                       : (A + (size_t)(512 + r) * 512);
      const float sgn = (top && !left) ? -1.f : 1.f;
      float4 v0 = *(const float4*)(src + col);
      float4 v1 = *(const float4*)(src + col + 4);
      float vv[8] = {v0.x, v0.y, v0.z, v0.w, v1.x, v1.y, v1.z, v1.w};
      short h[8], l[8];
#pragma unroll
      for (int i = 0; i < 8; ++i) {
        short2 s = split1(sgn * vv[i]);
        h[i] = s.x; l[i] = s.y;
      }
      __syncthreads();
      *(bf16x8*)&sAh[sm * 40 + sk] = *(bf16x8*)h;
      *(bf16x8*)&sAl[sm * 40 + sk] = *(bf16x8*)l;
      __syncthreads();
    }

    // gather + split B fragments (B_stack is [1024][512], k-major gather)
    bf16x8 bh[2], bl[2];
#pragma unroll
    for (int nt = 0; nt < 2; ++nt) {
      const float* bp = B + (size_t)(k0 + q * 8) * 512 + bn + wn + nt * 16 + l15;
      short hh[8], ll[8];
#pragma unroll
      for (int j = 0; j < 8; ++j) {
        short2 s = split1(bp[(size_t)j * 512]);
        hh[j] = s.x; ll[j] = s.y;
      }
      bh[nt] = *(bf16x8*)hh;
      bl[nt] = *(bf16x8*)ll;
    }

    // read A fragments
    bf16x8 ah[2], al[2];
#pragma unroll
    for (int mt = 0; mt < 2; ++mt) {
      const int m = wm + mt * 16 + l15;
      ah[mt] = *(const bf16x8*)&sAh[m * 40 + q * 8];
      al[mt] = *(const bf16x8*)&sAl[m * 40 + q * 8];
    }

#pragma unroll
    for (int mt = 0; mt < 2; ++mt)
#pragma unroll
      for (int nt = 0; nt < 2; ++nt) {
        acc[mt][nt] = __builtin_amdgcn_mfma_f32_16x16x32_bf16(ah[mt], bh[nt], acc[mt][nt], 0, 0, 0);
        acc[mt][nt] = __builtin_amdgcn_mfma_f32_16x16x32_bf16(ah[mt], bl[nt], acc[mt][nt], 0, 0, 0);
        acc[mt][nt] = __builtin_amdgcn_mfma_f32_16x16x32_bf16(al[mt], bh[nt], acc[mt][nt], 0, 0, 0);
      }
  }

#pragma unroll
  for (int mt = 0; mt < 2; ++mt)
#pragma unroll
    for (int nt = 0; nt < 2; ++nt)
#pragma unroll
      for (int r = 0; r < 4; ++r) {
        const int gm = bm + wm + mt * 16 + q * 4 + r;
        const int gn = bn + wn + nt * 16 + l15;
        C[(size_t)gm * 512 + gn] = acc[mt][nt][r];
      }
}

// ---------------------------------------------------------------------------
// XPREP: split x[512][8192] into bf16 hi/lo in MFMA-fragment order.
// xp layout: [g=kt*4+q][n] -> 16 shorts: [0..7]=hi(j), [8..15]=lo(j),
// where element j corresponds to x[g*8+j][n]. One thread per (g,n):
// 8 coalesced dword loads (stride 32KB), 2 b128 stores (block-contiguous).
// ---------------------------------------------------------------------------
__global__ __launch_bounds__(256) void xprep_kernel(
    const float* __restrict__ x, short* __restrict__ xp) {
  const int t = blockIdx.x * 256 + threadIdx.x;  // 0..524287
  const int n = t & 8191;
  const int g = t >> 13;  // 0..63
  const float* src = x + (size_t)g * 8 * BATCH + n;
  short h[8], l[8];
#pragma unroll
  for (int j = 0; j < 8; ++j) {
    short2 s = split1(src[(size_t)j * BATCH]);
    h[j] = s.x; l[j] = s.y;
  }
  short* dst = xp + (size_t)t * 16;
  *(bf16x8*)dst = *(bf16x8*)h;
  *(bf16x8*)(dst + 8) = *(bf16x8*)l;
}

// ---------------------------------------------------------------------------
// APPLY v2 (MFMA, bf16-split, packed-B): C[1024x8192] = A[1024x512] * x.
// B comes from xp (fragment-ordered bf16 hi/lo): 2 coalesced b128 loads per
// nt per k-tile instead of 8 scalar dword gathers + 8 splits.
// BM=64, BN=128, BK=32; grid (64,16) = 1024 blocks (4/CU, 16 waves/CU).
// Wave tile 32x64: acc[2][4]. Numerically identical to v1 (same split,
// same MFMA k-order).
// ---------------------------------------------------------------------------
__global__ __launch_bounds__(256) void gemm_mfma_packed(
    const float* __restrict__ A, const short* __restrict__ xp,
    float* __restrict__ C) {
  __shared__ short sAh[64 * 40], sAl[64 * 40];

  const int tid = threadIdx.x;
  const int lane = tid & 63;
  const int w = tid >> 6;
  const int bm = blockIdx.y * 64;
  const int bn = blockIdx.x * 128;
  const int wm = (w & 1) * 32;
  const int wn = (w >> 1) * 64;
  const int q = lane >> 4;
  const int l15 = lane & 15;

  const int sm = tid >> 2;          // 0..63 staged row
  const int sk = (tid & 3) * 8;     // 0,8,16,24
  const float* Ap = A + (size_t)(bm + sm) * 512 + sk;

  f32x4 acc[2][4];
#pragma unroll
  for (int i = 0; i < 2; ++i)
#pragma unroll
    for (int j = 0; j < 4; ++j) acc[i][j] = (f32x4){0.f, 0.f, 0.f, 0.f};

  // prefetch first A slab (8 floats/thread)
  float4 pa[2];
  pa[0] = *(const float4*)(Ap);
  pa[1] = *(const float4*)(Ap + 4);

#pragma unroll 1
  for (int k0 = 0; k0 < 512; k0 += 32) {
    // stage A slab
    {
      short h[8], l[8];
#pragma unroll
      for (int i = 0; i < 8; ++i) {
        short2 s = split1(((const float*)pa)[i]);
        h[i] = s.x; l[i] = s.y;
      }
      __syncthreads();
      *(bf16x8*)&sAh[sm * 40 + sk] = *(bf16x8*)h;
      *(bf16x8*)&sAl[sm * 40 + sk] = *(bf16x8*)l;
      __syncthreads();
    }

    // prefetch next A slab
    if (k0 + 32 < 512) {
      pa[0] = *(const float4*)(Ap + k0 + 32);
      pa[1] = *(const float4*)(Ap + k0 + 36);
    }

    // B fragments: packed coalesced loads
    const int kt = k0 >> 5;
    bf16x8 bh[4], bl[4];
#pragma unroll
    for (int nt = 0; nt < 4; ++nt) {
      const short* bp = xp + (((size_t)(kt * 4 + q)) * BATCH +
                              (bn + wn + nt * 16 + l15)) * 16;
      bh[nt] = *(const bf16x8*)bp;
      bl[nt] = *(const bf16x8*)(bp + 8);
    }

    // read A fragments
    bf16x8 ah[2], al[2];
#pragma unroll
    for (int mt = 0; mt < 2; ++mt) {
      const int m = wm + mt * 16 + l15;
      ah[mt] = *(const bf16x8*)&sAh[m * 40 + q * 8];
      al[mt] = *(const bf16x8*)&sAl[m * 40 + q * 8];
    }

#pragma unroll
    for (int mt = 0; mt < 2; ++mt)
#pragma unroll
      for (int nt = 0; nt < 4; ++nt) {
        acc[mt][nt] = __builtin_amdgcn_mfma_f32_16x16x32_bf16(ah[mt], bh[nt], acc[mt][nt], 0, 0, 0);
        acc[mt][nt] = __builtin_amdgcn_mfma_f32_16x16x32_bf16(ah[mt], bl[nt], acc[mt][nt], 0, 0, 0);
        acc[mt][nt] = __builtin_amdgcn_mfma_f32_16x16x32_bf16(al[mt], bh[nt], acc[mt][nt], 0, 0, 0);
      }
  }

  // epilogue: D[row=q*4+r][col=l15] per 16x16 tile
#pragma unroll
  for (int mt = 0; mt < 2; ++mt)
#pragma unroll
    for (int nt = 0; nt < 4; ++nt)
#pragma unroll
      for (int r = 0; r < 4; ++r) {
        const int gm = bm + wm + mt * 16 + q * 4 + r;
        const int gn = bn + wn + nt * 16 + l15;
        C[(size_t)gm * BATCH + gn] = acc[mt][nt][r];
      }
}

// ---------------------------------------------------------------------------
// APPLY v1 (legacy fallback, verified): per-lane k-major dword gather.
// ---------------------------------------------------------------------------
__global__ __launch_bounds__(256) void gemm_mfma(
    const float* __restrict__ A, const float* __restrict__ B,
    float* __restrict__ C) {
  __shared__ short sAh[128 * 40], sAl[128 * 40];

  const int tid = threadIdx.x;
  const int lane = tid & 63;
  const int w = tid >> 6;
  const int bm = blockIdx.y * 128;
  const int bn = blockIdx.x * 128;
  const int wm = (w & 1) * 64;
  const int wn = (w >> 1) * 64;
  const int q = lane >> 4;
  const int l15 = lane & 15;

  const int sm = tid >> 1;
  const int sk = (tid & 1) * 16;
  const float* Ap = A + (size_t)(bm + sm) * 512 + sk;

  f32x4 acc[4][4];
#pragma unroll
  for (int i = 0; i < 4; ++i)
#pragma unroll
    for (int j = 0; j < 4; ++j) acc[i][j] = (f32x4){0.f, 0.f, 0.f, 0.f};

  float4 pa[4];
#pragma unroll
  for (int i = 0; i < 4; ++i) pa[i] = *(const float4*)(Ap + i * 4);

#pragma unroll 1
  for (int k0 = 0; k0 < 512; k0 += 32) {
    {
      short h[16], l[16];
#pragma unroll
      for (int i = 0; i < 16; ++i) {
        short2 s = split1(((const float*)pa)[i]);
        h[i] = s.x; l[i] = s.y;
      }
      __syncthreads();
      *(bf16x8*)&sAh[sm * 40 + sk]     = *(bf16x8*)&h[0];
      *(bf16x8*)&sAh[sm * 40 + sk + 8] = *(bf16x8*)&h[8];
      *(bf16x8*)&sAl[sm * 40 + sk]     = *(bf16x8*)&l[0];
      *(bf16x8*)&sAl[sm * 40 + sk + 8] = *(bf16x8*)&l[8];
      __syncthreads();
    }

    if (k0 + 32 < 512) {
#pragma unroll
      for (int i = 0; i < 4; ++i) pa[i] = *(const float4*)(Ap + k0 + 32 + i * 4);
    }

    bf16x8 bh[4], bl[4];
#pragma unroll
    for (int nt = 0; nt < 4; ++nt) {
      const float* bp = B + (size_t)(k0 + q * 8) * BATCH + bn + wn + nt * 16 + l15;
      short hh[8], ll[8];
#pragma unroll
      for (int j = 0; j < 8; ++j) {
        short2 s = split1(bp[(size_t)j * BATCH]);
        hh[j] = s.x; ll[j] = s.y;
      }
      bh[nt] = *(bf16x8*)hh;
      bl[nt] = *(bf16x8*)ll;
    }

    bf16x8 ah[4], al[4];
#pragma unroll
    for (int mt = 0; mt < 4; ++mt) {
      const int m = wm + mt * 16 + l15;
      ah[mt] = *(const bf16x8*)&sAh[m * 40 + q * 8];
      al[mt] = *(const bf16x8*)&sAl[m * 40 + q * 8];
    }

#pragma unroll
    for (int mt = 0; mt < 4; ++mt)
#pragma unroll
      for (int nt = 0; nt < 4; ++nt) {
        acc[mt][nt] = __builtin_amdgcn_mfma_f32_16x16x32_bf16(ah[mt], bh[nt], acc[mt][nt], 0, 0, 0);
        acc[mt][nt] = __builtin_amdgcn_mfma_f32_16x16x32_bf16(ah[mt], bl[nt], acc[mt][nt], 0, 0, 0);
        acc[mt][nt] = __builtin_amdgcn_mfma_f32_16x16x32_bf16(al[mt], bh[nt], acc[mt][nt], 0, 0, 0);
      }
  }

#pragma unroll
  for (int mt = 0; mt < 4; ++mt)
#pragma unroll
    for (int nt = 0; nt < 4; ++nt)
#pragma unroll
      for (int r = 0; r < 4; ++r) {
        const int gm = bm + wm + mt * 16 + q * 4 + r;
        const int gn = bn + wn + nt * 16 + l15;
        C[(size_t)gm * BATCH + gn] = acc[mt][nt][r];
      }
}

extern "C" void kernel_launch(void* const* d_in, const int* in_sizes, int n_in,
                              void* d_out, int out_size, void* d_ws, size_t ws_size,
                              hipStream_t stream) {
  const float* x      = (const float*)d_in[0];
  const float* thetas = (const float*)d_in[1];
  const float* phis   = (const float*)d_in[2];
  const float* gammas = (const float*)d_in[3];
  const float* bse    = (const float*)d_in[4];
  const float* lse    = (const float*)d_in[5];

  float* base = (float*)d_ws;
  float4* pp  = (float4*)d_ws;
  const size_t PPF   = 1048576;   // 4 MB of floats (pp region)
  const size_t SEGSZ = 524288;    // 2 MB per seg transfer matrix

  precomp_kernel<<<512, 256, 0, stream>>>(thetas, phis, bse, lse, pp);

  if (ws_size >= (size_t)24 * 1024 * 1024) {
    // Fast plan (ws >= 24 MB, proven available in round 2): nseg=4 compose +
    // merges, then packed-x apply.
    // Layout (MB): [0,4) pp -> later Tf@[0,2); [4,12) T0..T3;
    //              [12,14) T10; [14,16) T32; xp @ [2,18.8) after merges.
    float* segs = base + PPF;
    compose_kernel<<<512, 256, 0, stream>>>(gammas, pp, segs, 64);

    float* T0  = segs + 0 * SEGSZ;
    float* T1  = segs + 1 * SEGSZ;
    float* T2  = segs + 2 * SEGSZ;
    float* T3  = segs + 3 * SEGSZ;
    float* T10 = segs + 4 * SEGSZ;   // [12,14)
    float* T32 = segs + 5 * SEGSZ;   // [14,16)
    float* Tf  = base;               // [0,2), pp dead after compose
    merge_mfma<<<dim3(8, 16, 2), 256, 0, stream>>>(T1, T0, T10, T3, T2, T32);
    merge_mfma<<<dim3(8, 16, 1), 256, 0, stream>>>(T32, T10, Tf, T32, T10, Tf);

    // x pre-pack over dead regions [2,18.8)
    short* xp = (short*)(base + SEGSZ);
    xprep_kernel<<<2048, 256, 0, stream>>>(x, xp);

    gemm_mfma_packed<<<dim3(64, 16), 256, 0, stream>>>(Tf, xp, (float*)d_out);
  } else {
    // Legacy plan (verified rounds 0-1).
    int nseg;
    if (ws_size >= (size_t)14 * 1024 * 1024)      nseg = 4;
    else if (ws_size >= (size_t)8 * 1024 * 1024)  nseg = 2;
    else                                          nseg = 1;

    float* segs = base + PPF;
    float* Tf;
    compose_kernel<<<nseg * 128, 256, 0, stream>>>(gammas, pp, segs, 256 / nseg);

    if (nseg == 4) {
      float* T0  = segs + 0 * SEGSZ;
      float* T1  = segs + 1 * SEGSZ;
      float* T2  = segs + 2 * SEGSZ;
      float* T3  = segs + 3 * SEGSZ;
      float* T10 = base;
      float* T32 = base + SEGSZ;
      Tf = segs + 4 * SEGSZ;
      merge_mfma<<<dim3(8, 16, 2), 256, 0, stream>>>(T1, T0, T10, T3, T2, T32);
      merge_mfma<<<dim3(8, 16, 1), 256, 0, stream>>>(T32, T10, Tf, T32, T10, Tf);
    } else if (nseg == 2) {
      float* T0 = segs + 0 * SEGSZ;
      float* T1 = segs + 1 * SEGSZ;
      Tf = base;
      merge_mfma<<<dim3(8, 16, 1), 256, 0, stream>>>(T1, T0, Tf, T1, T0, Tf);
    } else {
      Tf = segs;
    }

    gemm_mfma<<<dim3(BATCH / 128, 8), 256, 0, stream>>>(Tf, x, (float*)d_out);
  }
}

// Round 4
// 262.846 us; speedup vs baseline: 1.3312x; 1.0149x over previous
//
#include <hip/hip_runtime.h>
#include <math.h>

#define BATCH 8192
#define NROW 512
#define NCOL 512
#define MNODE 256

typedef __attribute__((ext_vector_type(8))) short bf16x8;
typedef __attribute__((ext_vector_type(4))) float f32x4;

// Split fp32 into truncated-bf16 hi + bf16(lo residual). a ~= hi + lo.
__device__ __forceinline__ short2 split1(float x) {
  unsigned u = __float_as_uint(x);
  short h = (short)(u >> 16);
  float r = x - __uint_as_float(u & 0xffff0000u);
  short l = (short)(__float_as_uint(r) >> 16);
  return make_short2(h, l);
}

// ---------------------------------------------------------------------------
// Fused per-node 2x2 complex matrix (verified).
// pp[2n+0]=(n11r,n11i,n12r,n12i); pp[2n+1]=(n21r,n21i,n22r,n22i)
// ---------------------------------------------------------------------------
__global__ __launch_bounds__(256) void precomp_kernel(
    const float* __restrict__ thetas, const float* __restrict__ phis,
    const float* __restrict__ bse, const float* __restrict__ lse,
    float4* __restrict__ pp) {
  int n = blockIdx.x * 256 + threadIdx.x;
  float th = thetas[n], ph = phis[n];
  float e0 = bse[2 * n + 0], e1 = bse[2 * n + 1];
  float l0 = lse[2 * n + 0], l1 = lse[2 * n + 1];
  const float K = 0.16609640474436813f;  // log2(10)/20
  float ins0 = exp2f(l0 * K), ins1 = exp2f(l1 * K);
  const float PI4 = 0.7853981633974483f;
  float s0, c0, s1, c1, sp, cp, st, ct;
  sincosf(PI4 + e0, &s0, &c0);
  sincosf(PI4 + e1, &s1, &c1);
  sincosf(ph, &sp, &cp);
  sincosf(th, &st, &ct);
  float AL = ins0 * s0, C1L = c0, C2L = ins0 * c0, SL = s0;
  float AR = ins1 * s1, C1R = c1, C2R = ins1 * c1, SR = s1;
  float a11r = AL * cp,   a11i = AL * sp;
  float a12r = 0.f,       a12i = C1L;
  float a21r = -C2L * sp, a21i = C2L * cp;
  float a22r = SL,        a22i = 0.f;
  float b11r = a11r * ct - a11i * st, b11i = a11r * st + a11i * ct;
  float b12r = a12r * ct - a12i * st, b12i = a12r * st + a12i * ct;
  float n11r = AR * b11r - C1R * a21i;
  float n11i = AR * b11i + C1R * a21r;
  float n12r = AR * b12r - C1R * a22i;
  float n12i = AR * b12i + C1R * a22r;
  float n21r = -C2R * b11i + SR * a21r;
  float n21i =  C2R * b11r + SR * a21i;
  float n22r = -C2R * b12i + SR * a22r;
  float n22i =  C2R * b12r + SR * a22i;
  pp[2 * n + 0] = make_float4(n11r, n11i, n12r, n12i);
  pp[2 * n + 1] = make_float4(n21r, n21i, n22r, n22i);
}

__device__ __forceinline__ void proc_pair(float& vtr, float& vti, float& vbr, float& vbi,
                                          const float4 q0, const float4 q1) {
  float tr = q0.x * vtr - q0.y * vti + q0.z * vbr - q0.w * vbi;
  float ti = q0.x * vti + q0.y * vtr + q0.z * vbi + q0.w * vbr;
  float br = q1.x * vtr - q1.y * vti + q1.z * vbr - q1.w * vbi;
  float bi = q1.x * vti + q1.y * vtr + q1.z * vbi + q1.w * vbr;
  vtr = tr; vti = ti; vbr = br; vbi = bi;
}

__device__ __forceinline__ int swz(int b) { return b ^ ((b >> 3) & 7); }

// ---------------------------------------------------------------------------
// SEGMENTED COMPOSE with BAND PREDICATION (round-1 verified structure).
// Changes this round: ep epilogue buffer UNIONed into buf (LDS 53248->32768,
// allows 4 blocks/CU) — safe because ep is only written after the loop's
// final __syncthreads, when all buf reads are complete.
// ---------------------------------------------------------------------------
__global__ __launch_bounds__(256) void compose_kernel(
    const float* __restrict__ gammas, const float4* __restrict__ pp,
    float* __restrict__ Tsegs, int pairs_per_seg) {
  __shared__ float4 buf[2][1024];              // 32 KB; reused as ep after loop
  float* epf = (float*)buf;                    // ep[i][j] == epf[i*5+j], 20 KB

  const int tid  = threadIdx.x;
  const int lane = tid & 63;
  const int w    = tid >> 6;
  const int seg  = blockIdx.x >> 7;
  const int g    = blockIdx.x & 127;
  const int col  = g * 4 + w;
  const int colmin = g * 4;   // block-uniform band center for staging

  const float4* ps = pp + (size_t)seg * pairs_per_seg * 1024;
  float* T = Tsegs + (size_t)seg * (1024 * NROW);

  float vr[8], vi[8];
#pragma unroll
  for (int r = 0; r < 8; ++r) {
    const int row = lane * 8 + r;
    vr[r] = 0.f; vi[r] = 0.f;
    if (row == col) {
      if (seg == 0) {
        float sg, cg;
        sincosf(gammas[row], &sg, &cg);
        vr[r] = cg; vi[r] = sg;
      } else {
        vr[r] = 1.f;
      }
    }
  }

  {
    const int sw = swz(tid);
#pragma unroll
    for (int k = 0; k < 4; ++k)
      buf[0][256 * k + sw] = ps[256 * k + tid];
  }
  __syncthreads();

  const int Lc = col >> 3;  // center lane of this wave's band

#pragma unroll 1
  for (int p = 0; p < pairs_per_seg; ++p) {
    const int b = p & 1;

    const int HA = (p >> 2) + 3;
    const bool act  = (lane >= Lc - HA)     && (lane <= Lc + HA);
    const bool wide = (lane >= Lc - HA - 1) && (lane <= Lc + HA + 1);

    float4 f0, f1, f2, f3;
    bool st0 = false, st1 = false;
    if (p < pairs_per_seg - 1) {
      const int slo = colmin - 2 * p - 50;
      const int shi = colmin + 2 * p + 53;
      st0 = (tid + 1 >= slo) && (tid <= shi);
      st1 = (tid + 257 >= slo) && (tid + 256 <= shi);
      const float4* src = ps + (size_t)(p + 1) * 1024;
      if (st0) { f0 = src[tid];       f2 = src[512 + tid]; }
      if (st1) { f1 = src[256 + tid]; f3 = src[768 + tid]; }
    }

    float4 pe[8], po[7], pu1;
    if (act) {
      const int base = 8 * lane;
      const int l7 = lane & 7;
#pragma unroll
      for (int j = 0; j < 8; ++j) pe[j] = buf[b][base + (j ^ l7)];
#pragma unroll
      for (int j = 0; j < 7; ++j) po[j] = buf[b][512 + base + (j ^ l7)];
      const int lm = (lane == 0) ? 0 : lane - 1;
      pu1 = buf[b][512 + 8 * lm + (7 ^ (lm & 7))];

#pragma unroll
      for (int k = 0; k < 4; ++k)
        proc_pair(vr[2 * k], vi[2 * k], vr[2 * k + 1], vi[2 * k + 1],
                  pe[2 * k], pe[2 * k + 1]);

#pragma unroll
      for (int k = 0; k < 3; ++k)
        proc_pair(vr[2 * k + 1], vi[2 * k + 1], vr[2 * k + 2], vi[2 * k + 2],
                  po[2 * k], po[2 * k + 1]);
    }

    float br = 0.f, bi = 0.f, tu = 0.f, tv = 0.f;
    if (wide) {
      br = __shfl_down(vr[0], 1, 64);
      bi = __shfl_down(vi[0], 1, 64);
      tu = __shfl_up(vr[7], 1, 64);
      tv = __shfl_up(vi[7], 1, 64);
    }
    if (act) {
      float nAr = po[6].x * vr[7] - po[6].y * vi[7] + po[6].z * br - po[6].w * bi;
      float nAi = po[6].x * vi[7] + po[6].y * vr[7] + po[6].z * bi + po[6].w * br;
      float nBr = pu1.x * tu - pu1.y * tv + pu1.z * vr[0] - pu1.w * vi[0];
      float nBi = pu1.x * tv + pu1.y * tu + pu1.z * vi[0] + pu1.w * vr[0];
      if (lane < 63) { vr[7] = nAr; vi[7] = nAi; }
      if (lane > 0)  { vr[0] = nBr; vi[0] = nBi; }
    }

    if (p < pairs_per_seg - 1) {
      const int sw = swz(tid);
      if (st0) { buf[1 - b][sw] = f0;       buf[1 - b][512 + sw] = f2; }
      if (st1) { buf[1 - b][256 + sw] = f1; buf[1 - b][768 + sw] = f3; }
    }
    __syncthreads();
  }

  // epilogue: all buf reads completed before the final barrier above.
#pragma unroll
  for (int r = 0; r < 8; ++r) {
    epf[(lane * 8 + r) * 5 + w] = vr[r];
    epf[(512 + lane * 8 + r) * 5 + w] = vi[r];
  }
  __syncthreads();
#pragma unroll
  for (int k = 0; k < 4; ++k) {
    const int i = k * 256 + tid;
    *(float4*)(T + (size_t)i * NROW + g * 4) =
        make_float4(epf[i * 5 + 0], epf[i * 5 + 1], epf[i * 5 + 2], epf[i * 5 + 3]);
  }
}

// ---------------------------------------------------------------------------
// MERGE, generalized + BAND-AWARE (MFMA, bf16-split): complex 512^3 as real
// GEMM  C_stack[1024x512] = A'[1024x1024] * B_stack[1024x512].
// A/B/C selected by blockIdx.z via base+z*stride (strides in floats, may be
// negative). A has exact complex band |r-c|<=HA, B |r-c|<=HB (segment of P
// pair-columns has support +-2P — same invariant as compose predication;
// entries outside are exact zeros). Per output tile we restrict the K loop
// to [rmin-HA, rmax+HA] ∩ [cmin-HB, cmax+HB]; skipped terms are exact-zero
// products, so results are bit-identical to the dense loop. K order (real
// half then imag half) matches the original dense kernel.
// ---------------------------------------------------------------------------
__global__ __launch_bounds__(256) void merge_g(
    const float* __restrict__ Ab, const float* __restrict__ Bb,
    float* __restrict__ Cb, long sA, long sB, long sC, int HA, int HB) {
  const float* A = Ab + (long)blockIdx.z * sA;
  const float* B = Bb + (long)blockIdx.z * sB;
  float*       C = Cb + (long)blockIdx.z * sC;

  __shared__ short sAh[64 * 40], sAl[64 * 40];  // [m][k] bf16, stride 40

  const int tid = threadIdx.x;
  const int lane = tid & 63;
  const int w = tid >> 6;
  const int bm = blockIdx.y * 64;
  const int bn = blockIdx.x * 64;
  const int wm = (w & 1) * 32;
  const int wn = (w >> 1) * 32;
  const int q = lane >> 4;
  const int l15 = lane & 15;

  const int sm = tid >> 2;          // 0..63 staged row
  const int sk = (tid & 3) * 8;     // 0..24 staged k-offset

  // band-limited K window (block-uniform)
  const int rmin = (blockIdx.y & 7) * 64;
  int klo = rmin - HA;
  {
    int t = bn - HB;
    if (t > klo) klo = t;
    if (klo < 0) klo = 0;
  }
  int khi = rmin + 63 + HA;
  {
    int t = bn + 63 + HB;
    if (t < khi) khi = t;
    if (khi > 511) khi = 511;
  }
  klo &= ~31;

  f32x4 acc[2][2];
#pragma unroll
  for (int i = 0; i < 2; ++i)
#pragma unroll
    for (int j = 0; j < 2; ++j) acc[i][j] = (f32x4){0.f, 0.f, 0.f, 0.f};

  if (klo <= khi) {
#pragma unroll 1
    for (int h = 0; h < 2; ++h) {
#pragma unroll 1
      for (int k0 = klo; k0 <= khi; k0 += 32) {
        const int gkb = h * 512 + k0;
        // stage A' tile [64m x 32k] with quadrant select + sign
        {
          const int gm = bm + sm;
          const int gk = gkb + sk;
          const int r = gm & 511;
          const bool top = gm < 512;
          const bool left = gk < 512;
          const int col = gk & 511;
          const float* src = (top == left) ? (A + (size_t)r * 512)
                                           : (A + (size_t)(512 + r) * 512);
          const float sgn = (top && !left) ? -1.f : 1.f;
          float4 v0 = *(const float4*)(src + col);
          float4 v1 = *(const float4*)(src + col + 4);
          float vv[8] = {v0.x, v0.y, v0.z, v0.w, v1.x, v1.y, v1.z, v1.w};
          short hh[8], ll[8];
#pragma unroll
          for (int i = 0; i < 8; ++i) {
            short2 s = split1(sgn * vv[i]);
            hh[i] = s.x; ll[i] = s.y;
          }
          __syncthreads();
          *(bf16x8*)&sAh[sm * 40 + sk] = *(bf16x8*)hh;
          *(bf16x8*)&sAl[sm * 40 + sk] = *(bf16x8*)ll;
          __syncthreads();
        }

        // gather + split B fragments (B_stack is [1024][512], k-major gather)
        bf16x8 bh[2], bl[2];
#pragma unroll
        for (int nt = 0; nt < 2; ++nt) {
          const float* bp = B + (size_t)(gkb + q * 8) * 512 + bn + wn + nt * 16 + l15;
          short hh[8], ll[8];
#pragma unroll
          for (int j = 0; j < 8; ++j) {
            short2 s = split1(bp[(size_t)j * 512]);
            hh[j] = s.x; ll[j] = s.y;
          }
          bh[nt] = *(bf16x8*)hh;
          bl[nt] = *(bf16x8*)ll;
        }

        // read A fragments
        bf16x8 ah[2], al[2];
#pragma unroll
        for (int mt = 0; mt < 2; ++mt) {
          const int m = wm + mt * 16 + l15;
          ah[mt] = *(const bf16x8*)&sAh[m * 40 + q * 8];
          al[mt] = *(const bf16x8*)&sAl[m * 40 + q * 8];
        }

#pragma unroll
        for (int mt = 0; mt < 2; ++mt)
#pragma unroll
          for (int nt = 0; nt < 2; ++nt) {
            acc[mt][nt] = __builtin_amdgcn_mfma_f32_16x16x32_bf16(ah[mt], bh[nt], acc[mt][nt], 0, 0, 0);
            acc[mt][nt] = __builtin_amdgcn_mfma_f32_16x16x32_bf16(ah[mt], bl[nt], acc[mt][nt], 0, 0, 0);
            acc[mt][nt] = __builtin_amdgcn_mfma_f32_16x16x32_bf16(al[mt], bh[nt], acc[mt][nt], 0, 0, 0);
          }
      }
    }
  }

#pragma unroll
  for (int mt = 0; mt < 2; ++mt)
#pragma unroll
    for (int nt = 0; nt < 2; ++nt)
#pragma unroll
      for (int r = 0; r < 4; ++r) {
        const int gm = bm + wm + mt * 16 + q * 4 + r;
        const int gn = bn + wn + nt * 16 + l15;
        C[(size_t)gm * 512 + gn] = acc[mt][nt][r];
      }
}

// ---------------------------------------------------------------------------
// XPREP: split x[512][8192] into bf16 hi/lo in MFMA-fragment order.
// xp layout: [g=kt*4+q][n] -> 16 shorts: [0..7]=hi(j), [8..15]=lo(j),
// element j = x[g*8+j][n].
// ---------------------------------------------------------------------------
__global__ __launch_bounds__(256) void xprep_kernel(
    const float* __restrict__ x, short* __restrict__ xp) {
  const int t = blockIdx.x * 256 + threadIdx.x;  // 0..524287
  const int n = t & 8191;
  const int g = t >> 13;  // 0..63
  const float* src = x + (size_t)g * 8 * BATCH + n;
  short h[8], l[8];
#pragma unroll
  for (int j = 0; j < 8; ++j) {
    short2 s = split1(src[(size_t)j * BATCH]);
    h[j] = s.x; l[j] = s.y;
  }
  short* dst = xp + (size_t)t * 16;
  *(bf16x8*)dst = *(bf16x8*)h;
  *(bf16x8*)(dst + 8) = *(bf16x8*)l;
}

// ---------------------------------------------------------------------------
// APPLY v2 (MFMA, bf16-split, packed-B): C[1024x8192] = A[1024x512] * x.
// BM=64, BN=128, BK=32; grid (64,16) = 1024 blocks. (verified round 3)
// ---------------------------------------------------------------------------
__global__ __launch_bounds__(256) void gemm_mfma_packed(
    const float* __restrict__ A, const short* __restrict__ xp,
    float* __restrict__ C) {
  __shared__ short sAh[64 * 40], sAl[64 * 40];

  const int tid = threadIdx.x;
  const int lane = tid & 63;
  const int w = tid >> 6;
  const int bm = blockIdx.y * 64;
  const int bn = blockIdx.x * 128;
  const int wm = (w & 1) * 32;
  const int wn = (w >> 1) * 64;
  const int q = lane >> 4;
  const int l15 = lane & 15;

  const int sm = tid >> 2;          // 0..63 staged row
  const int sk = (tid & 3) * 8;     // 0,8,16,24
  const float* Ap = A + (size_t)(bm + sm) * 512 + sk;

  f32x4 acc[2][4];
#pragma unroll
  for (int i = 0; i < 2; ++i)
#pragma unroll
    for (int j = 0; j < 4; ++j) acc[i][j] = (f32x4){0.f, 0.f, 0.f, 0.f};

  float4 pa[2];
  pa[0] = *(const float4*)(Ap);
  pa[1] = *(const float4*)(Ap + 4);

#pragma unroll 1
  for (int k0 = 0; k0 < 512; k0 += 32) {
    {
      short h[8], l[8];
#pragma unroll
      for (int i = 0; i < 8; ++i) {
        short2 s = split1(((const float*)pa)[i]);
        h[i] = s.x; l[i] = s.y;
      }
      __syncthreads();
      *(bf16x8*)&sAh[sm * 40 + sk] = *(bf16x8*)h;
      *(bf16x8*)&sAl[sm * 40 + sk] = *(bf16x8*)l;
      __syncthreads();
    }

    if (k0 + 32 < 512) {
      pa[0] = *(const float4*)(Ap + k0 + 32);
      pa[1] = *(const float4*)(Ap + k0 + 36);
    }

    const int kt = k0 >> 5;
    bf16x8 bh[4], bl[4];
#pragma unroll
    for (int nt = 0; nt < 4; ++nt) {
      const short* bp = xp + (((size_t)(kt * 4 + q)) * BATCH +
                              (bn + wn + nt * 16 + l15)) * 16;
      bh[nt] = *(const bf16x8*)bp;
      bl[nt] = *(const bf16x8*)(bp + 8);
    }

    bf16x8 ah[2], al[2];
#pragma unroll
    for (int mt = 0; mt < 2; ++mt) {
      const int m = wm + mt * 16 + l15;
      ah[mt] = *(const bf16x8*)&sAh[m * 40 + q * 8];
      al[mt] = *(const bf16x8*)&sAl[m * 40 + q * 8];
    }

#pragma unroll
    for (int mt = 0; mt < 2; ++mt)
#pragma unroll
      for (int nt = 0; nt < 4; ++nt) {
        acc[mt][nt] = __builtin_amdgcn_mfma_f32_16x16x32_bf16(ah[mt], bh[nt], acc[mt][nt], 0, 0, 0);
        acc[mt][nt] = __builtin_amdgcn_mfma_f32_16x16x32_bf16(ah[mt], bl[nt], acc[mt][nt], 0, 0, 0);
        acc[mt][nt] = __builtin_amdgcn_mfma_f32_16x16x32_bf16(al[mt], bh[nt], acc[mt][nt], 0, 0, 0);
      }
  }

#pragma unroll
  for (int mt = 0; mt < 2; ++mt)
#pragma unroll
    for (int nt = 0; nt < 4; ++nt)
#pragma unroll
      for (int r = 0; r < 4; ++r) {
        const int gm = bm + wm + mt * 16 + q * 4 + r;
        const int gn = bn + wn + nt * 16 + l15;
        C[(size_t)gm * BATCH + gn] = acc[mt][nt][r];
      }
}

// ---------------------------------------------------------------------------
// APPLY v1 (legacy fallback, verified): per-lane k-major dword gather.
// ---------------------------------------------------------------------------
__global__ __launch_bounds__(256) void gemm_mfma(
    const float* __restrict__ A, const float* __restrict__ B,
    float* __restrict__ C) {
  __shared__ short sAh[128 * 40], sAl[128 * 40];

  const int tid = threadIdx.x;
  const int lane = tid & 63;
  const int w = tid >> 6;
  const int bm = blockIdx.y * 128;
  const int bn = blockIdx.x * 128;
  const int wm = (w & 1) * 64;
  const int wn = (w >> 1) * 64;
  const int q = lane >> 4;
  const int l15 = lane & 15;

  const int sm = tid >> 1;
  const int sk = (tid & 1) * 16;
  const float* Ap = A + (size_t)(bm + sm) * 512 + sk;

  f32x4 acc[4][4];
#pragma unroll
  for (int i = 0; i < 4; ++i)
#pragma unroll
    for (int j = 0; j < 4; ++j) acc[i][j] = (f32x4){0.f, 0.f, 0.f, 0.f};

  float4 pa[4];
#pragma unroll
  for (int i = 0; i < 4; ++i) pa[i] = *(const float4*)(Ap + i * 4);

#pragma unroll 1
  for (int k0 = 0; k0 < 512; k0 += 32) {
    {
      short h[16], l[16];
#pragma unroll
      for (int i = 0; i < 16; ++i) {
        short2 s = split1(((const float*)pa)[i]);
        h[i] = s.x; l[i] = s.y;
      }
      __syncthreads();
      *(bf16x8*)&sAh[sm * 40 + sk]     = *(bf16x8*)&h[0];
      *(bf16x8*)&sAh[sm * 40 + sk + 8] = *(bf16x8*)&h[8];
      *(bf16x8*)&sAl[sm * 40 + sk]     = *(bf16x8*)&l[0];
      *(bf16x8*)&sAl[sm * 40 + sk + 8] = *(bf16x8*)&l[8];
      __syncthreads();
    }

    if (k0 + 32 < 512) {
#pragma unroll
      for (int i = 0; i < 4; ++i) pa[i] = *(const float4*)(Ap + k0 + 32 + i * 4);
    }

    bf16x8 bh[4], bl[4];
#pragma unroll
    for (int nt = 0; nt < 4; ++nt) {
      const float* bp = B + (size_t)(k0 + q * 8) * BATCH + bn + wn + nt * 16 + l15;
      short hh[8], ll[8];
#pragma unroll
      for (int j = 0; j < 8; ++j) {
        short2 s = split1(bp[(size_t)j * BATCH]);
        hh[j] = s.x; ll[j] = s.y;
      }
      bh[nt] = *(bf16x8*)hh;
      bl[nt] = *(bf16x8*)ll;
    }

    bf16x8 ah[4], al[4];
#pragma unroll
    for (int mt = 0; mt < 4; ++mt) {
      const int m = wm + mt * 16 + l15;
      ah[mt] = *(const bf16x8*)&sAh[m * 40 + q * 8];
      al[mt] = *(const bf16x8*)&sAl[m * 40 + q * 8];
    }

#pragma unroll
    for (int mt = 0; mt < 4; ++mt)
#pragma unroll
      for (int nt = 0; nt < 4; ++nt) {
        acc[mt][nt] = __builtin_amdgcn_mfma_f32_16x16x32_bf16(ah[mt], bh[nt], acc[mt][nt], 0, 0, 0);
        acc[mt][nt] = __builtin_amdgcn_mfma_f32_16x16x32_bf16(ah[mt], bl[nt], acc[mt][nt], 0, 0, 0);
        acc[mt][nt] = __builtin_amdgcn_mfma_f32_16x16x32_bf16(al[mt], bh[nt], acc[mt][nt], 0, 0, 0);
      }
  }

#pragma unroll
  for (int mt = 0; mt < 4; ++mt)
#pragma unroll
    for (int nt = 0; nt < 4; ++nt)
#pragma unroll
      for (int r = 0; r < 4; ++r) {
        const int gm = bm + wm + mt * 16 + q * 4 + r;
        const int gn = bn + wn + nt * 16 + l15;
        C[(size_t)gm * BATCH + gn] = acc[mt][nt][r];
      }
}

extern "C" void kernel_launch(void* const* d_in, const int* in_sizes, int n_in,
                              void* d_out, int out_size, void* d_ws, size_t ws_size,
                              hipStream_t stream) {
  const float* x      = (const float*)d_in[0];
  const float* thetas = (const float*)d_in[1];
  const float* phis   = (const float*)d_in[2];
  const float* gammas = (const float*)d_in[3];
  const float* bse    = (const float*)d_in[4];
  const float* lse    = (const float*)d_in[5];

  float* base = (float*)d_ws;
  float4* pp  = (float4*)d_ws;
  const long PPF   = 1048576;   // 4 MB of floats (pp region)
  const long S     = 524288;    // 2 MB per seg transfer matrix (floats)

  precomp_kernel<<<512, 256, 0, stream>>>(thetas, phis, bse, lse, pp);

  if (ws_size >= (size_t)24 * 1024 * 1024) {
    // nseg=8 plan (ws >= 24 MB proven in round 2).
    // Layout (MB): pp [0,4); T0..T7 [4,20); U0 [20,22); U1 [22,24);
    //   U2 [0,2); U3 [2,4)  (pp dead after compose);
    //   V0 [4,6); V1 [6,8)  (T0..T3 dead after L1);
    //   Tf [0,2) (U2 dead after L2); xp [2,18.78) (all dead by then).
    float* segs = base + PPF;
    compose_kernel<<<1024, 256, 0, stream>>>(gammas, pp, segs, 32);

    float* U0 = base + 5 * PPF;          // 20 MB
    float* U1 = base + 5 * PPF + S;      // 22 MB
    float* U2 = base;                    // 0 MB
    float* U3 = base + S;                // 2 MB
    // L1 (seg band +-64, margin 68): (T1,T0)->U0, (T3,T2)->U1
    merge_g<<<dim3(8, 16, 2), 256, 0, stream>>>(
        segs + S, segs, U0, 2 * S, 2 * S, S, 68, 68);
    // (T5,T4)->U2, (T7,T6)->U3
    merge_g<<<dim3(8, 16, 2), 256, 0, stream>>>(
        segs + 5 * S, segs + 4 * S, U2, 2 * S, 2 * S, S, 68, 68);
    // L2 (band +-128, margin 136): (U1,U0)->V0, (U3,U2)->V1
    float* V0 = base + PPF;              // 4 MB
    float* V1 = base + PPF + S;          // 6 MB
    merge_g<<<dim3(8, 16, 2), 256, 0, stream>>>(
        U1, U0, V0, (long)(U3 - U1), (long)(U2 - U0), S, 136, 136);
    // L3 (band +-256, margin 272): (V1,V0)->Tf
    float* Tf = base;
    merge_g<<<dim3(8, 16, 1), 256, 0, stream>>>(V1, V0, Tf, 0, 0, 0, 272, 272);

    short* xp = (short*)(base + S);
    xprep_kernel<<<2048, 256, 0, stream>>>(x, xp);

    gemm_mfma_packed<<<dim3(64, 16), 256, 0, stream>>>(Tf, xp, (float*)d_out);
  } else {
    // Legacy plans with band-aware merges.
    int nseg;
    if (ws_size >= (size_t)14 * 1024 * 1024)      nseg = 4;
    else if (ws_size >= (size_t)8 * 1024 * 1024)  nseg = 2;
    else                                          nseg = 1;

    float* segs = base + PPF;
    float* Tf;
    compose_kernel<<<nseg * 128, 256, 0, stream>>>(gammas, pp, segs, 256 / nseg);

    if (nseg == 4) {
      // seg band +-128 (P=64) -> margin 132; level-2 inputs +-256 -> 264.
      float* T10 = base;
      float* T32 = base + S;
      Tf = segs + 4 * S;
      merge_g<<<dim3(8, 16, 2), 256, 0, stream>>>(
          segs + S, segs, T10, 2 * S, 2 * S, S, 132, 132);
      merge_g<<<dim3(8, 16, 1), 256, 0, stream>>>(
          T32, T10, Tf, 0, 0, 0, 264, 264);
    } else if (nseg == 2) {
      // seg band +-256 (P=128) -> margin 260.
      Tf = base;
      merge_g<<<dim3(8, 16, 1), 256, 0, stream>>>(
          segs + S, segs, Tf, 0, 0, 0, 260, 260);
    } else {
      Tf = segs;
    }

    gemm_mfma<<<dim3(BATCH / 128, 8), 256, 0, stream>>>(Tf, x, (float*)d_out);
  }
}

// Round 5
// 227.009 us; speedup vs baseline: 1.5414x; 1.1579x over previous
//
#include <hip/hip_runtime.h>
#include <math.h>

#define BATCH 8192
#define NROW 512
#define NCOL 512
#define MNODE 256

typedef __attribute__((ext_vector_type(8))) short bf16x8;
typedef __attribute__((ext_vector_type(4))) float f32x4;

// Split fp32 into truncated-bf16 hi + bf16(lo residual). a ~= hi + lo.
__device__ __forceinline__ short2 split1(float x) {
  unsigned u = __float_as_uint(x);
  short h = (short)(u >> 16);
  float r = x - __uint_as_float(u & 0xffff0000u);
  short l = (short)(__float_as_uint(r) >> 16);
  return make_short2(h, l);
}

// ---------------------------------------------------------------------------
// Fused per-node 2x2 complex matrix (verified).
// pp[2n+0]=(n11r,n11i,n12r,n12i); pp[2n+1]=(n21r,n21i,n22r,n22i)
// ---------------------------------------------------------------------------
__global__ __launch_bounds__(256) void precomp_kernel(
    const float* __restrict__ thetas, const float* __restrict__ phis,
    const float* __restrict__ bse, const float* __restrict__ lse,
    float4* __restrict__ pp) {
  int n = blockIdx.x * 256 + threadIdx.x;
  float th = thetas[n], ph = phis[n];
  float e0 = bse[2 * n + 0], e1 = bse[2 * n + 1];
  float l0 = lse[2 * n + 0], l1 = lse[2 * n + 1];
  const float K = 0.16609640474436813f;  // log2(10)/20
  float ins0 = exp2f(l0 * K), ins1 = exp2f(l1 * K);
  const float PI4 = 0.7853981633974483f;
  float s0, c0, s1, c1, sp, cp, st, ct;
  sincosf(PI4 + e0, &s0, &c0);
  sincosf(PI4 + e1, &s1, &c1);
  sincosf(ph, &sp, &cp);
  sincosf(th, &st, &ct);
  float AL = ins0 * s0, C1L = c0, C2L = ins0 * c0, SL = s0;
  float AR = ins1 * s1, C1R = c1, C2R = ins1 * c1, SR = s1;
  float a11r = AL * cp,   a11i = AL * sp;
  float a12r = 0.f,       a12i = C1L;
  float a21r = -C2L * sp, a21i = C2L * cp;
  float a22r = SL,        a22i = 0.f;
  float b11r = a11r * ct - a11i * st, b11i = a11r * st + a11i * ct;
  float b12r = a12r * ct - a12i * st, b12i = a12r * st + a12i * ct;
  float n11r = AR * b11r - C1R * a21i;
  float n11i = AR * b11i + C1R * a21r;
  float n12r = AR * b12r - C1R * a22i;
  float n12i = AR * b12i + C1R * a22r;
  float n21r = -C2R * b11i + SR * a21r;
  float n21i =  C2R * b11r + SR * a21i;
  float n22r = -C2R * b12i + SR * a22r;
  float n22i =  C2R * b12r + SR * a22i;
  pp[2 * n + 0] = make_float4(n11r, n11i, n12r, n12i);
  pp[2 * n + 1] = make_float4(n21r, n21i, n22r, n22i);
}

__device__ __forceinline__ void proc_pair(float& vtr, float& vti, float& vbr, float& vbi,
                                          const float4 q0, const float4 q1) {
  float tr = q0.x * vtr - q0.y * vti + q0.z * vbr - q0.w * vbi;
  float ti = q0.x * vti + q0.y * vtr + q0.z * vbi + q0.w * vbr;
  float br = q1.x * vtr - q1.y * vti + q1.z * vbr - q1.w * vbi;
  float bi = q1.x * vti + q1.y * vtr + q1.z * vbi + q1.w * vbr;
  vtr = tr; vti = ti; vbr = br; vbi = bi;
}

__device__ __forceinline__ int swz(int b) { return b ^ ((b >> 3) & 7); }

// ---------------------------------------------------------------------------
// BAND-COMPACT COMPOSE (round 5). One wave = one basis column `col`.
// Support after p pair-columns is exactly within [col-2p, col+2p]; at P=32
// this is <=129 rows. Lane l holds rows (E, E+1), E = colA + 2*lane,
// colA = (col-63)&~1  -> 128 slots cover all but ONE spill row (col+-64,
// parity-dependent) which only becomes nonzero in the FINAL iteration's odd
// phase and is computed in closed form from the post-even boundary value.
// Per iter: 4 coalesced float4 weight loads (lane l -> node colA/2+l, 32B
// contiguous per lane), one even 2x2, one odd 2x2 with 4 lane-shuffles.
// No LDS, no barriers in the loop. Validity predicates are lane-static:
//   even pair (E,E+1)   node E/2      valid iff 0<=E<=510
//   odd  top  row E+1    node E/2      valid iff 0<=E<=508  (node<=254)
//   odd  bot  row E      node E/2-1    valid iff 2<=E<=510
// Out-of-range lanes keep exact zeros; boundary shuffle operands are exact
// zeros (spill destinations are never sources). Math per 2x2 is the exact
// proc_pair expression — bit-compatible with the verified kernel.
// ---------------------------------------------------------------------------
__global__ __launch_bounds__(256) void compose_band(
    const float* __restrict__ gammas, const float4* __restrict__ pp,
    float* __restrict__ Tsegs, int P) {
  __shared__ float ep[5120];  // [row(0..511)=re, 512+row=im][5] transpose buffer

  const int tid  = threadIdx.x;
  const int lane = tid & 63;
  const int w    = tid >> 6;
  const int seg  = blockIdx.x >> 7;
  const int g    = blockIdx.x & 127;
  const int col  = g * 4 + w;

  const float4* ps = pp + (size_t)seg * P * 1024;
  float* T = Tsegs + (size_t)seg * (1024 * NROW);

  const int colA = (col - 63) & ~1;        // even, slots [colA, colA+127]
  const int E    = colA + 2 * lane;        // my even row; rows E, E+1
  const int je   = E >> 1;
  const int jeC  = je < 0 ? 0 : (je > 255 ? 255 : je);

  const bool vE  = (E >= 0) && (E <= 510);
  const bool vOT = (E >= 0) && (E <= 508);
  const bool vOB = (E >= 2) && (E <= 510);

  float ar = 0.f, ai = 0.f, br = 0.f, bi = 0.f;
  {
    float vr0 = 1.f, vi0 = 0.f;
    if (seg == 0) {
      float sg, cg;
      sincosf(gammas[col], &sg, &cg);
      vr0 = cg; vi0 = sg;
    }
    if (E == col)     { ar = vr0; ai = vi0; }
    if (E + 1 == col) { br = vr0; bi = vi0; }
  }

  const float4* pe = ps + 2 * jeC;        // even node jeC: q0=pe[0], q1=pe[1]
  const float4* po = ps + 512 + 2 * jeC;  // odd node jeC: q0=po[0]; node jeC-1 q1=po[-1]

  float sar = 0.f, sai = 0.f, sbr = 0.f, sbi = 0.f;  // post-even snapshot (last iter)

  for (int p = 0; p < P; ++p) {
    float4 q0 = pe[0];
    float4 q1 = pe[1];
    float4 o0 = po[0];
    float4 o1 = po[-1];
    pe += 1024; po += 1024;

    // even pair (E, E+1): vt=(ar,ai), vb=(br,bi)
    {
      float tr = q0.x * ar - q0.y * ai + q0.z * br - q0.w * bi;
      float ti = q0.x * ai + q0.y * ar + q0.z * bi + q0.w * br;
      float ur = q1.x * ar - q1.y * ai + q1.z * br - q1.w * bi;
      float ui = q1.x * ai + q1.y * ar + q1.z * bi + q1.w * br;
      if (vE) { ar = tr; ai = ti; br = ur; bi = ui; }
    }

    if (p == P - 1) { sar = ar; sai = ai; sbr = br; sbi = bi; }

    // odd phase: neighbor values post-even
    float anr = __shfl_down(ar, 1, 64);   // v[E+2]
    float ani = __shfl_down(ai, 1, 64);
    float bpr = __shfl_up(br, 1, 64);     // v[E-1]
    float bpi = __shfl_up(bi, 1, 64);
    if (lane == 63) { anr = 0.f; ani = 0.f; }  // row colA+128: zero as source
    if (lane == 0)  { bpr = 0.f; bpi = 0.f; }  // row colA-1:  zero as source
    {
      // top: row E+1 is top of pair (E+1, E+2), node je: vt=b, vb=a_next
      float tr = o0.x * br - o0.y * bi + o0.z * anr - o0.w * ani;
      float ti = o0.x * bi + o0.y * br + o0.z * ani + o0.w * anr;
      // bottom: row E is bottom of pair (E-1, E), node je-1: vt=b_prev, vb=a
      float ur = o1.x * bpr - o1.y * bpi + o1.z * ar - o1.w * ai;
      float ui = o1.x * bpi + o1.y * bpr + o1.z * ai + o1.w * ar;
      if (vOT) { br = tr; bi = ti; }
      if (vOB) { ar = ur; ai = ui; }
    }
  }

  // spill row (exactly one, final odd phase, closed form)
  int sprow = -1;
  float spr = 0.f, spi = 0.f;
  if ((col & 1) == 0) {
    if (colA + 128 <= 511) {
      sprow = colA + 128;  // = col+64; bottom of pair (colA+127, colA+128)
      float4 w1 = ps[(size_t)(P - 1) * 1024 + 512 + 2 * (colA / 2 + 63) + 1];
      float vtr = __shfl(sbr, 63, 64);   // v[colA+127] post-even (lane 63 b)
      float vti = __shfl(sbi, 63, 64);
      spr = w1.x * vtr - w1.y * vti;     // vb = 0
      spi = w1.x * vti + w1.y * vtr;
    }
  } else {
    if (colA - 1 >= 0) {
      sprow = colA - 1;    // = col-64; top of pair (colA-1, colA)
      float4 w0 = ps[(size_t)(P - 1) * 1024 + 512 + 2 * (colA / 2 - 1)];
      float vbr = __shfl(sar, 0, 64);    // v[colA] post-even (lane 0 a)
      float vbi = __shfl(sai, 0, 64);
      spr = w0.z * vbr - w0.w * vbi;     // vt = 0
      spi = w0.z * vbi + w0.w * vbr;
    }
  }

  // epilogue: zero transpose buffer, deposit band + spill, write full column
  for (int i = tid; i < 5120; i += 256) ep[i] = 0.f;
  __syncthreads();
  if (E >= 0 && E <= 510) {
    ep[E * 5 + w]         = ar;
    ep[(512 + E) * 5 + w] = ai;
    ep[(E + 1) * 5 + w]       = br;
    ep[(513 + E) * 5 + w]     = bi;
  }
  if (lane == 0 && sprow >= 0) {
    ep[sprow * 5 + w]         = spr;
    ep[(512 + sprow) * 5 + w] = spi;
  }
  __syncthreads();
#pragma unroll
  for (int k = 0; k < 4; ++k) {
    const int i = k * 256 + tid;
    *(float4*)(T + (size_t)i * NROW + g * 4) =
        make_float4(ep[i * 5 + 0], ep[i * 5 + 1], ep[i * 5 + 2], ep[i * 5 + 3]);
  }
}

// ---------------------------------------------------------------------------
// LEGACY COMPOSE (verified; used for ws < 24 MB plans with larger P).
// ---------------------------------------------------------------------------
__global__ __launch_bounds__(256) void compose_kernel(
    const float* __restrict__ gammas, const float4* __restrict__ pp,
    float* __restrict__ Tsegs, int pairs_per_seg) {
  __shared__ float4 buf[2][1024];
  float* epf = (float*)buf;

  const int tid  = threadIdx.x;
  const int lane = tid & 63;
  const int w    = tid >> 6;
  const int seg  = blockIdx.x >> 7;
  const int g    = blockIdx.x & 127;
  const int col  = g * 4 + w;
  const int colmin = g * 4;

  const float4* ps = pp + (size_t)seg * pairs_per_seg * 1024;
  float* T = Tsegs + (size_t)seg * (1024 * NROW);

  float vr[8], vi[8];
#pragma unroll
  for (int r = 0; r < 8; ++r) {
    const int row = lane * 8 + r;
    vr[r] = 0.f; vi[r] = 0.f;
    if (row == col) {
      if (seg == 0) {
        float sg, cg;
        sincosf(gammas[row], &sg, &cg);
        vr[r] = cg; vi[r] = sg;
      } else {
        vr[r] = 1.f;
      }
    }
  }

  {
    const int sw = swz(tid);
#pragma unroll
    for (int k = 0; k < 4; ++k)
      buf[0][256 * k + sw] = ps[256 * k + tid];
  }
  __syncthreads();

  const int Lc = col >> 3;

#pragma unroll 1
  for (int p = 0; p < pairs_per_seg; ++p) {
    const int b = p & 1;

    const int HA = (p >> 2) + 3;
    const bool act  = (lane >= Lc - HA)     && (lane <= Lc + HA);
    const bool wide = (lane >= Lc - HA - 1) && (lane <= Lc + HA + 1);

    float4 f0, f1, f2, f3;
    bool st0 = false, st1 = false;
    if (p < pairs_per_seg - 1) {
      const int slo = colmin - 2 * p - 50;
      const int shi = colmin + 2 * p + 53;
      st0 = (tid + 1 >= slo) && (tid <= shi);
      st1 = (tid + 257 >= slo) && (tid + 256 <= shi);
      const float4* src = ps + (size_t)(p + 1) * 1024;
      if (st0) { f0 = src[tid];       f2 = src[512 + tid]; }
      if (st1) { f1 = src[256 + tid]; f3 = src[768 + tid]; }
    }

    float4 pe[8], po[7], pu1;
    if (act) {
      const int base = 8 * lane;
      const int l7 = lane & 7;
#pragma unroll
      for (int j = 0; j < 8; ++j) pe[j] = buf[b][base + (j ^ l7)];
#pragma unroll
      for (int j = 0; j < 7; ++j) po[j] = buf[b][512 + base + (j ^ l7)];
      const int lm = (lane == 0) ? 0 : lane - 1;
      pu1 = buf[b][512 + 8 * lm + (7 ^ (lm & 7))];

#pragma unroll
      for (int k = 0; k < 4; ++k)
        proc_pair(vr[2 * k], vi[2 * k], vr[2 * k + 1], vi[2 * k + 1],
                  pe[2 * k], pe[2 * k + 1]);

#pragma unroll
      for (int k = 0; k < 3; ++k)
        proc_pair(vr[2 * k + 1], vi[2 * k + 1], vr[2 * k + 2], vi[2 * k + 2],
                  po[2 * k], po[2 * k + 1]);
    }

    float br = 0.f, bi = 0.f, tu = 0.f, tv = 0.f;
    if (wide) {
      br = __shfl_down(vr[0], 1, 64);
      bi = __shfl_down(vi[0], 1, 64);
      tu = __shfl_up(vr[7], 1, 64);
      tv = __shfl_up(vi[7], 1, 64);
    }
    if (act) {
      float nAr = po[6].x * vr[7] - po[6].y * vi[7] + po[6].z * br - po[6].w * bi;
      float nAi = po[6].x * vi[7] + po[6].y * vr[7] + po[6].z * bi + po[6].w * br;
      float nBr = pu1.x * tu - pu1.y * tv + pu1.z * vr[0] - pu1.w * vi[0];
      float nBi = pu1.x * tv + pu1.y * tu + pu1.z * vi[0] + pu1.w * vr[0];
      if (lane < 63) { vr[7] = nAr; vi[7] = nAi; }
      if (lane > 0)  { vr[0] = nBr; vi[0] = nBi; }
    }

    if (p < pairs_per_seg - 1) {
      const int sw = swz(tid);
      if (st0) { buf[1 - b][sw] = f0;       buf[1 - b][512 + sw] = f2; }
      if (st1) { buf[1 - b][256 + sw] = f1; buf[1 - b][768 + sw] = f3; }
    }
    __syncthreads();
  }

#pragma unroll
  for (int r = 0; r < 8; ++r) {
    epf[(lane * 8 + r) * 5 + w] = vr[r];
    epf[(512 + lane * 8 + r) * 5 + w] = vi[r];
  }
  __syncthreads();
#pragma unroll
  for (int k = 0; k < 4; ++k) {
    const int i = k * 256 + tid;
    *(float4*)(T + (size_t)i * NROW + g * 4) =
        make_float4(epf[i * 5 + 0], epf[i * 5 + 1], epf[i * 5 + 2], epf[i * 5 + 3]);
  }
}

// ---------------------------------------------------------------------------
// MERGE, generalized + BAND-AWARE (verified round 4).
// ---------------------------------------------------------------------------
__global__ __launch_bounds__(256) void merge_g(
    const float* __restrict__ Ab, const float* __restrict__ Bb,
    float* __restrict__ Cb, long sA, long sB, long sC, int HA, int HB) {
  const float* A = Ab + (long)blockIdx.z * sA;
  const float* B = Bb + (long)blockIdx.z * sB;
  float*       C = Cb + (long)blockIdx.z * sC;

  __shared__ short sAh[64 * 40], sAl[64 * 40];  // [m][k] bf16, stride 40

  const int tid = threadIdx.x;
  const int lane = tid & 63;
  const int w = tid >> 6;
  const int bm = blockIdx.y * 64;
  const int bn = blockIdx.x * 64;
  const int wm = (w & 1) * 32;
  const int wn = (w >> 1) * 32;
  const int q = lane >> 4;
  const int l15 = lane & 15;

  const int sm = tid >> 2;          // 0..63 staged row
  const int sk = (tid & 3) * 8;     // 0..24 staged k-offset

  // band-limited K window (block-uniform)
  const int rmin = (blockIdx.y & 7) * 64;
  int klo = rmin - HA;
  {
    int t = bn - HB;
    if (t > klo) klo = t;
    if (klo < 0) klo = 0;
  }
  int khi = rmin + 63 + HA;
  {
    int t = bn + 63 + HB;
    if (t < khi) khi = t;
    if (khi > 511) khi = 511;
  }
  klo &= ~31;

  f32x4 acc[2][2];
#pragma unroll
  for (int i = 0; i < 2; ++i)
#pragma unroll
    for (int j = 0; j < 2; ++j) acc[i][j] = (f32x4){0.f, 0.f, 0.f, 0.f};

  if (klo <= khi) {
#pragma unroll 1
    for (int h = 0; h < 2; ++h) {
#pragma unroll 1
      for (int k0 = klo; k0 <= khi; k0 += 32) {
        const int gkb = h * 512 + k0;
        // stage A' tile [64m x 32k] with quadrant select + sign
        {
          const int gm = bm + sm;
          const int gk = gkb + sk;
          const int r = gm & 511;
          const bool top = gm < 512;
          const bool left = gk < 512;
          const int col = gk & 511;
          const float* src = (top == left) ? (A + (size_t)r * 512)
                                           : (A + (size_t)(512 + r) * 512);
          const float sgn = (top && !left) ? -1.f : 1.f;
          float4 v0 = *(const float4*)(src + col);
          float4 v1 = *(const float4*)(src + col + 4);
          float vv[8] = {v0.x, v0.y, v0.z, v0.w, v1.x, v1.y, v1.z, v1.w};
          short hh[8], ll[8];
#pragma unroll
          for (int i = 0; i < 8; ++i) {
            short2 s = split1(sgn * vv[i]);
            hh[i] = s.x; ll[i] = s.y;
          }
          __syncthreads();
          *(bf16x8*)&sAh[sm * 40 + sk] = *(bf16x8*)hh;
          *(bf16x8*)&sAl[sm * 40 + sk] = *(bf16x8*)ll;
          __syncthreads();
        }

        // gather + split B fragments (B_stack is [1024][512], k-major gather)
        bf16x8 bh[2], bl[2];
#pragma unroll
        for (int nt = 0; nt < 2; ++nt) {
          const float* bp = B + (size_t)(gkb + q * 8) * 512 + bn + wn + nt * 16 + l15;
          short hh[8], ll[8];
#pragma unroll
          for (int j = 0; j < 8; ++j) {
            short2 s = split1(bp[(size_t)j * 512]);
            hh[j] = s.x; ll[j] = s.y;
          }
          bh[nt] = *(bf16x8*)hh;
          bl[nt] = *(bf16x8*)ll;
        }

        // read A fragments
        bf16x8 ah[2], al[2];
#pragma unroll
        for (int mt = 0; mt < 2; ++mt) {
          const int m = wm + mt * 16 + l15;
          ah[mt] = *(const bf16x8*)&sAh[m * 40 + q * 8];
          al[mt] = *(const bf16x8*)&sAl[m * 40 + q * 8];
        }

#pragma unroll
        for (int mt = 0; mt < 2; ++mt)
#pragma unroll
          for (int nt = 0; nt < 2; ++nt) {
            acc[mt][nt] = __builtin_amdgcn_mfma_f32_16x16x32_bf16(ah[mt], bh[nt], acc[mt][nt], 0, 0, 0);
            acc[mt][nt] = __builtin_amdgcn_mfma_f32_16x16x32_bf16(ah[mt], bl[nt], acc[mt][nt], 0, 0, 0);
            acc[mt][nt] = __builtin_amdgcn_mfma_f32_16x16x32_bf16(al[mt], bh[nt], acc[mt][nt], 0, 0, 0);
          }
      }
    }
  }

#pragma unroll
  for (int mt = 0; mt < 2; ++mt)
#pragma unroll
    for (int nt = 0; nt < 2; ++nt)
#pragma unroll
      for (int r = 0; r < 4; ++r) {
        const int gm = bm + wm + mt * 16 + q * 4 + r;
        const int gn = bn + wn + nt * 16 + l15;
        C[(size_t)gm * 512 + gn] = acc[mt][nt][r];
      }
}

// ---------------------------------------------------------------------------
// XPREP: split x[512][8192] into bf16 hi/lo in MFMA-fragment order.
// ---------------------------------------------------------------------------
__global__ __launch_bounds__(256) void xprep_kernel(
    const float* __restrict__ x, short* __restrict__ xp) {
  const int t = blockIdx.x * 256 + threadIdx.x;  // 0..524287
  const int n = t & 8191;
  const int g = t >> 13;  // 0..63
  const float* src = x + (size_t)g * 8 * BATCH + n;
  short h[8], l[8];
#pragma unroll
  for (int j = 0; j < 8; ++j) {
    short2 s = split1(src[(size_t)j * BATCH]);
    h[j] = s.x; l[j] = s.y;
  }
  short* dst = xp + (size_t)t * 16;
  *(bf16x8*)dst = *(bf16x8*)h;
  *(bf16x8*)(dst + 8) = *(bf16x8*)l;
}

// ---------------------------------------------------------------------------
// APPLY v2 (MFMA, bf16-split, packed-B): C[1024x8192] = A[1024x512] * x.
// BM=64, BN=128, BK=32; grid (64,16) = 1024 blocks. (verified round 3)
// ---------------------------------------------------------------------------
__global__ __launch_bounds__(256) void gemm_mfma_packed(
    const float* __restrict__ A, const short* __restrict__ xp,
    float* __restrict__ C) {
  __shared__ short sAh[64 * 40], sAl[64 * 40];

  const int tid = threadIdx.x;
  const int lane = tid & 63;
  const int w = tid >> 6;
  const int bm = blockIdx.y * 64;
  const int bn = blockIdx.x * 128;
  const int wm = (w & 1) * 32;
  const int wn = (w >> 1) * 64;
  const int q = lane >> 4;
  const int l15 = lane & 15;

  const int sm = tid >> 2;          // 0..63 staged row
  const int sk = (tid & 3) * 8;     // 0,8,16,24
  const float* Ap = A + (size_t)(bm + sm) * 512 + sk;

  f32x4 acc[2][4];
#pragma unroll
  for (int i = 0; i < 2; ++i)
#pragma unroll
    for (int j = 0; j < 4; ++j) acc[i][j] = (f32x4){0.f, 0.f, 0.f, 0.f};

  float4 pa[2];
  pa[0] = *(const float4*)(Ap);
  pa[1] = *(const float4*)(Ap + 4);

#pragma unroll 1
  for (int k0 = 0; k0 < 512; k0 += 32) {
    {
      short h[8], l[8];
#pragma unroll
      for (int i = 0; i < 8; ++i) {
        short2 s = split1(((const float*)pa)[i]);
        h[i] = s.x; l[i] = s.y;
      }
      __syncthreads();
      *(bf16x8*)&sAh[sm * 40 + sk] = *(bf16x8*)h;
      *(bf16x8*)&sAl[sm * 40 + sk] = *(bf16x8*)l;
      __syncthreads();
    }

    if (k0 + 32 < 512) {
      pa[0] = *(const float4*)(Ap + k0 + 32);
      pa[1] = *(const float4*)(Ap + k0 + 36);
    }

    const int kt = k0 >> 5;
    bf16x8 bh[4], bl[4];
#pragma unroll
    for (int nt = 0; nt < 4; ++nt) {
      const short* bp = xp + (((size_t)(kt * 4 + q)) * BATCH +
                              (bn + wn + nt * 16 + l15)) * 16;
      bh[nt] = *(const bf16x8*)bp;
      bl[nt] = *(const bf16x8*)(bp + 8);
    }

    bf16x8 ah[2], al[2];
#pragma unroll
    for (int mt = 0; mt < 2; ++mt) {
      const int m = wm + mt * 16 + l15;
      ah[mt] = *(const bf16x8*)&sAh[m * 40 + q * 8];
      al[mt] = *(const bf16x8*)&sAl[m * 40 + q * 8];
    }

#pragma unroll
    for (int mt = 0; mt < 2; ++mt)
#pragma unroll
      for (int nt = 0; nt < 4; ++nt) {
        acc[mt][nt] = __builtin_amdgcn_mfma_f32_16x16x32_bf16(ah[mt], bh[nt], acc[mt][nt], 0, 0, 0);
        acc[mt][nt] = __builtin_amdgcn_mfma_f32_16x16x32_bf16(ah[mt], bl[nt], acc[mt][nt], 0, 0, 0);
        acc[mt][nt] = __builtin_amdgcn_mfma_f32_16x16x32_bf16(al[mt], bh[nt], acc[mt][nt], 0, 0, 0);
      }
  }

#pragma unroll
  for (int mt = 0; mt < 2; ++mt)
#pragma unroll
    for (int nt = 0; nt < 4; ++nt)
#pragma unroll
      for (int r = 0; r < 4; ++r) {
        const int gm = bm + wm + mt * 16 + q * 4 + r;
        const int gn = bn + wn + nt * 16 + l15;
        C[(size_t)gm * BATCH + gn] = acc[mt][nt][r];
      }
}

// ---------------------------------------------------------------------------
// APPLY v1 (legacy fallback, verified): per-lane k-major dword gather.
// ---------------------------------------------------------------------------
__global__ __launch_bounds__(256) void gemm_mfma(
    const float* __restrict__ A, const float* __restrict__ B,
    float* __restrict__ C) {
  __shared__ short sAh[128 * 40], sAl[128 * 40];

  const int tid = threadIdx.x;
  const int lane = tid & 63;
  const int w = tid >> 6;
  const int bm = blockIdx.y * 128;
  const int bn = blockIdx.x * 128;
  const int wm = (w & 1) * 64;
  const int wn = (w >> 1) * 64;
  const int q = lane >> 4;
  const int l15 = lane & 15;

  const int sm = tid >> 1;
  const int sk = (tid & 1) * 16;
  const float* Ap = A + (size_t)(bm + sm) * 512 + sk;

  f32x4 acc[4][4];
#pragma unroll
  for (int i = 0; i < 4; ++i)
#pragma unroll
    for (int j = 0; j < 4; ++j) acc[i][j] = (f32x4){0.f, 0.f, 0.f, 0.f};

  float4 pa[4];
#pragma unroll
  for (int i = 0; i < 4; ++i) pa[i] = *(const float4*)(Ap + i * 4);

#pragma unroll 1
  for (int k0 = 0; k0 < 512; k0 += 32) {
    {
      short h[16], l[16];
#pragma unroll
      for (int i = 0; i < 16; ++i) {
        short2 s = split1(((const float*)pa)[i]);
        h[i] = s.x; l[i] = s.y;
      }
      __syncthreads();
      *(bf16x8*)&sAh[sm * 40 + sk]     = *(bf16x8*)&h[0];
      *(bf16x8*)&sAh[sm * 40 + sk + 8] = *(bf16x8*)&h[8];
      *(bf16x8*)&sAl[sm * 40 + sk]     = *(bf16x8*)&l[0];
      *(bf16x8*)&sAl[sm * 40 + sk + 8] = *(bf16x8*)&l[8];
      __syncthreads();
    }

    if (k0 + 32 < 512) {
#pragma unroll
      for (int i = 0; i < 4; ++i) pa[i] = *(const float4*)(Ap + k0 + 32 + i * 4);
    }

    bf16x8 bh[4], bl[4];
#pragma unroll
    for (int nt = 0; nt < 4; ++nt) {
      const float* bp = B + (size_t)(k0 + q * 8) * BATCH + bn + wn + nt * 16 + l15;
      short hh[8], ll[8];
#pragma unroll
      for (int j = 0; j < 8; ++j) {
        short2 s = split1(bp[(size_t)j * BATCH]);
        hh[j] = s.x; ll[j] = s.y;
      }
      bh[nt] = *(bf16x8*)hh;
      bl[nt] = *(bf16x8*)ll;
    }

    bf16x8 ah[4], al[4];
#pragma unroll
    for (int mt = 0; mt < 4; ++mt) {
      const int m = wm + mt * 16 + l15;
      ah[mt] = *(const bf16x8*)&sAh[m * 40 + q * 8];
      al[mt] = *(const bf16x8*)&sAl[m * 40 + q * 8];
    }

#pragma unroll
    for (int mt = 0; mt < 4; ++mt)
#pragma unroll
      for (int nt = 0; nt < 4; ++nt) {
        acc[mt][nt] = __builtin_amdgcn_mfma_f32_16x16x32_bf16(ah[mt], bh[nt], acc[mt][nt], 0, 0, 0);
        acc[mt][nt] = __builtin_amdgcn_mfma_f32_16x16x32_bf16(ah[mt], bl[nt], acc[mt][nt], 0, 0, 0);
        acc[mt][nt] = __builtin_amdgcn_mfma_f32_16x16x32_bf16(al[mt], bh[nt], acc[mt][nt], 0, 0, 0);
      }
  }

#pragma unroll
  for (int mt = 0; mt < 4; ++mt)
#pragma unroll
    for (int nt = 0; nt < 4; ++nt)
#pragma unroll
      for (int r = 0; r < 4; ++r) {
        const int gm = bm + wm + mt * 16 + q * 4 + r;
        const int gn = bn + wn + nt * 16 + l15;
        C[(size_t)gm * BATCH + gn] = acc[mt][nt][r];
      }
}

extern "C" void kernel_launch(void* const* d_in, const int* in_sizes, int n_in,
                              void* d_out, int out_size, void* d_ws, size_t ws_size,
                              hipStream_t stream) {
  const float* x      = (const float*)d_in[0];
  const float* thetas = (const float*)d_in[1];
  const float* phis   = (const float*)d_in[2];
  const float* gammas = (const float*)d_in[3];
  const float* bse    = (const float*)d_in[4];
  const float* lse    = (const float*)d_in[5];

  float* base = (float*)d_ws;
  float4* pp  = (float4*)d_ws;
  const long PPF   = 1048576;   // 4 MB of floats (pp region)
  const long S     = 524288;    // 2 MB per seg transfer matrix (floats)

  precomp_kernel<<<512, 256, 0, stream>>>(thetas, phis, bse, lse, pp);

  if (ws_size >= (size_t)24 * 1024 * 1024) {
    // nseg=8 plan (ws >= 24 MB proven in round 2). Layout as round 4.
    float* segs = base + PPF;
    compose_band<<<1024, 256, 0, stream>>>(gammas, pp, segs, 32);

    float* U0 = base + 5 * PPF;          // 20 MB
    float* U1 = base + 5 * PPF + S;      // 22 MB
    float* U2 = base;                    // 0 MB
    float* U3 = base + S;                // 2 MB
    merge_g<<<dim3(8, 16, 2), 256, 0, stream>>>(
        segs + S, segs, U0, 2 * S, 2 * S, S, 68, 68);
    merge_g<<<dim3(8, 16, 2), 256, 0, stream>>>(
        segs + 5 * S, segs + 4 * S, U2, 2 * S, 2 * S, S, 68, 68);
    float* V0 = base + PPF;              // 4 MB
    float* V1 = base + PPF + S;          // 6 MB
    merge_g<<<dim3(8, 16, 2), 256, 0, stream>>>(
        U1, U0, V0, (long)(U3 - U1), (long)(U2 - U0), S, 136, 136);
    float* Tf = base;
    merge_g<<<dim3(8, 16, 1), 256, 0, stream>>>(V1, V0, Tf, 0, 0, 0, 272, 272);

    short* xp = (short*)(base + S);
    xprep_kernel<<<2048, 256, 0, stream>>>(x, xp);

    gemm_mfma_packed<<<dim3(64, 16), 256, 0, stream>>>(Tf, xp, (float*)d_out);
  } else {
    // Legacy plans with band-aware merges.
    int nseg;
    if (ws_size >= (size_t)14 * 1024 * 1024)      nseg = 4;
    else if (ws_size >= (size_t)8 * 1024 * 1024)  nseg = 2;
    else                                          nseg = 1;

    float* segs = base + PPF;
    float* Tf;
    compose_kernel<<<nseg * 128, 256, 0, stream>>>(gammas, pp, segs, 256 / nseg);

    if (nseg == 4) {
      float* T10 = base;
      float* T32 = base + S;
      Tf = segs + 4 * S;
      merge_g<<<dim3(8, 16, 2), 256, 0, stream>>>(
          segs + S, segs, T10, 2 * S, 2 * S, S, 132, 132);
      merge_g<<<dim3(8, 16, 1), 256, 0, stream>>>(
          T32, T10, Tf, 0, 0, 0, 264, 264);
    } else if (nseg == 2) {
      Tf = base;
      merge_g<<<dim3(8, 16, 1), 256, 0, stream>>>(
          segs + S, segs, Tf, 0, 0, 0, 260, 260);
    } else {
      Tf = segs;
    }

    gemm_mfma<<<dim3(BATCH / 128, 8), 256, 0, stream>>>(Tf, x, (float*)d_out);
  }
}